// Round 11
// baseline (390.546 us; speedup 1.0000x reference)
//
#include <hip/hip_runtime.h>
#include <math.h>

#define IN_FEATS 128
#define HIDDEN   256
#define CLASSES  41
#define CPAD     64
#define LDA      264    // 256 + 8 pad (bf16 elems)
#define CHUNK    8192   // edges per block in passA/passB
#define BSH      7      // bucket = dst >> 7 (128 nodes per bucket)
#define NBMAX    1024   // max buckets (N <= 131072)

typedef __attribute__((ext_vector_type(8))) short short8;
typedef __attribute__((ext_vector_type(4))) float f32x4;
typedef __attribute__((ext_vector_type(2))) float f32x2;

__device__ __forceinline__ unsigned short f2bf(float f) {
    union { float f; unsigned u; } v; v.f = f;
    unsigned r = v.u + 0x7FFF + ((v.u >> 16) & 1);
    return (unsigned short)(r >> 16);
}
__device__ __forceinline__ float bf2f(unsigned short h) {
    union { unsigned u; float f; } v; v.u = ((unsigned)h) << 16;
    return v.f;
}

// ---- passA: per-chunk LDS histogram over buckets -> mat[b*NBLK + blk] ------
__global__ void __launch_bounds__(256)
passA_kernel(const int* __restrict__ dst, int* __restrict__ mat,
             int E, int NB, int NBLK) {
    __shared__ int hist[NBMAX];
    int blk = blockIdx.x, t = threadIdx.x;
    for (int b = t; b < NB; b += 256) hist[b] = 0;
    __syncthreads();
    int e0 = blk * CHUNK;
    for (int i = t; i < CHUNK; i += 256) {
        int e = e0 + i;
        if (e < E) atomicAdd(&hist[dst[e] >> BSH], 1);
    }
    __syncthreads();
    for (int b = t; b < NB; b += 256) mat[b * NBLK + blk] = hist[b];
}

// ---- scanOne: single-block exclusive scan of mat[0..L] (sentinel at L) -----
__global__ void __launch_bounds__(1024)
scanOne_kernel(int* __restrict__ a, int L) {
    __shared__ int lds[1024];
    __shared__ int carry_s;
    int t = threadIdx.x;
    if (t == 0) carry_s = 0;
    __syncthreads();
    for (int base = 0; base <= L; base += 4096) {
        int v[4];
        int s = 0;
#pragma unroll
        for (int i = 0; i < 4; ++i) {
            int idx = base + t * 4 + i;
            v[i] = (idx < L) ? a[idx] : 0;
            s += v[i];
        }
        lds[t] = s;
        __syncthreads();
        for (int off = 1; off < 1024; off <<= 1) {
            int val = lds[t];
            int add = (t >= off) ? lds[t - off] : 0;
            __syncthreads();
            lds[t] = val + add;
            __syncthreads();
        }
        int run = carry_s + ((t == 0) ? 0 : lds[t - 1]);
        int tot = lds[1023];
#pragma unroll
        for (int i = 0; i < 4; ++i) {
            int idx = base + t * 4 + i;
            if (idx <= L) a[idx] = run;
            run += v[i];
        }
        __syncthreads();
        if (t == 0) carry_s += tot;
        __syncthreads();
    }
}

// ---- passB: scatter packed (src<<7 | dst&127) to bucket-major tmp ----------
__global__ void __launch_bounds__(256)
passB_kernel(const int* __restrict__ src, const int* __restrict__ dst,
             const int* __restrict__ mat, unsigned* __restrict__ tmp,
             int E, int NB, int NBLK) {
    __shared__ int cursor[NBMAX];
    int blk = blockIdx.x, t = threadIdx.x;
    for (int b = t; b < NB; b += 256) cursor[b] = mat[b * NBLK + blk];
    __syncthreads();
    int e0 = blk * CHUNK;
    for (int i = t; i < CHUNK; i += 256) {
        int e = e0 + i;
        if (e < E) {
            int d = dst[e], s = src[e];
            int b = d >> BSH;
            int pos = atomicAdd(&cursor[b], 1);
            tmp[pos] = (unsigned)((s << BSH) | (d & 127));
        }
    }
}

// ---- passC: per-bucket fine CSR: row_start + csr_src -----------------------
__global__ void __launch_bounds__(256)
passC_kernel(const unsigned* __restrict__ tmp, const int* __restrict__ mat,
             int* __restrict__ row_start, int* __restrict__ csr_src,
             int E, int N, int NB, int NBLK) {
    __shared__ int h[128], cur[128], sc[128];
    int b = blockIdx.x, t = threadIdx.x;
    int segBase = mat[b * NBLK];
    int segEnd  = mat[(b + 1) * NBLK];
    int len = segEnd - segBase;
    if (t < 128) h[t] = 0;
    __syncthreads();
    for (int i = t; i < len; i += 256)
        atomicAdd(&h[tmp[segBase + i] & 127], 1);
    __syncthreads();
    if (t < 128) sc[t] = h[t];
    __syncthreads();
    for (int off = 1; off < 128; off <<= 1) {
        int v2 = 0;
        if (t < 128) { v2 = sc[t]; if (t >= off) v2 += sc[t - off]; }
        __syncthreads();
        if (t < 128) sc[t] = v2;
        __syncthreads();
    }
    if (t < 128) {
        int base = segBase + sc[t] - h[t];
        cur[t] = base;
        int n = (b << BSH) + t;
        if (n < N) row_start[n] = base;
    }
    if (b == NB - 1 && t == 0) row_start[N] = segEnd;
    __syncthreads();
    for (int i = t; i < len; i += 256) {
        unsigned w = tmp[segBase + i];
        int pos = atomicAdd(&cur[w & 127], 1);
        csr_src[pos] = (int)(w >> BSH);
    }
}

// ---- cvtprep: x -> bf16 + fp8 (blocks [0,XB)) ; weight pack (rest) ---------
__global__ void __launch_bounds__(256)
cvtprep_kernel(const float* __restrict__ x, unsigned short* __restrict__ xbf,
               unsigned* __restrict__ xf8, long n4, int XB,
               const float* __restrict__ W1l, const float* __restrict__ W1r,
               const float* __restrict__ W2l, const float* __restrict__ W2r,
               unsigned short* __restrict__ Bp1, unsigned short* __restrict__ Bp2) {
    int b = blockIdx.x, t = threadIdx.x;
    if (b < XB) {
        long i = (long)b * 256 + t;
        if (i < n4) {
            float4 v = *(const float4*)(x + i * 4);
            ushort4 o;
            o.x = f2bf(v.x); o.y = f2bf(v.y); o.z = f2bf(v.z); o.w = f2bf(v.w);
            *(ushort4*)(xbf + i * 4) = o;
            unsigned u = __builtin_amdgcn_cvt_pk_fp8_f32(v.x, v.y, 0, false);
            u = __builtin_amdgcn_cvt_pk_fp8_f32(v.z, v.w, u, true);
            xf8[i] = u;
        }
        return;
    }
    int idx = (b - XB) * 256 + t;
    if (idx < 256 * 256) {
        int k = idx >> 8, c = idx & 255;
        float v = (k < 128) ? W1l[k * 256 + c] : W1r[(k - 128) * 256 + c];
        Bp1[((k >> 5) * 256 + c) * 32 + ((k & 31) >> 3) * 8 + (k & 7)] = f2bf(v);
    } else {
        int j = idx - 65536;
        if (j < 256 * 96) {
            int k = j / 96, c = j % 96;
            float v = 0.0f;
            if (c < 41) v = W2l[k * 41 + c];
            else if (c >= 48 && c < 89) v = W2r[k * 41 + (c - 48)];
            Bp2[((k >> 5) * 96 + c) * 32 + ((k & 31) >> 3) * 8 + (k & 7)] = f2bf(v);
        }
    }
}

// ---- fused: gather1 (fp8 mean -> LDS) + h1 = relu([agg|x]@Bp1+b1) in LDS
//      + zb8 = fp8(h1@W2l), rbufb = bf16(h1@W2r + b2) ------------------------
__global__ void __launch_bounds__(256)
mgemm_fused_kernel(const unsigned short* __restrict__ xf8u,
                   const unsigned short* __restrict__ xbf,
                   const int* __restrict__ row_start, const int* __restrict__ csr_src,
                   const unsigned short* __restrict__ Bp1, const float* __restrict__ b1,
                   const unsigned short* __restrict__ Bp2, const float* __restrict__ b2,
                   unsigned char* __restrict__ zb8, unsigned short* __restrict__ rbufb,
                   int N) {
    __shared__ __align__(16) unsigned short alds[64 * LDA];
    int n0 = blockIdx.x * 64;
    int t = threadIdx.x;
    int wid = t >> 6, lane = t & 63;
    // ---- stage x-half (cols 128..255) ----
#pragma unroll
    for (int i = 0; i < 4; ++i) {
        int cid = t + i * 256;            // 1024 chunks of 16B
        int row = cid >> 4, cx = cid & 15;
        int gr = n0 + row;
        uint4 v = make_uint4(0, 0, 0, 0);
        if (gr < N) v = *(const uint4*)(xbf + (size_t)gr * 128 + cx * 8);
        *(uint4*)&alds[row * LDA + 128 + cx * 8] = v;
    }
    // ---- gather agg-half (cols 0..127): wave wid owns rows wid*16..+15 ----
    for (int k = 0; k < 16; ++k) {
        int row = (wid << 4) + k;
        int gr = n0 + row;
        float sl[8], sh[8];
#pragma unroll
        for (int j = 0; j < 8; ++j) { sl[j] = 0.f; sh[j] = 0.f; }
        int rs = 0, d = 0;
        if (gr < N) { rs = row_start[gr]; d = row_start[gr + 1] - rs; }
        int i = 0;
        for (; i + 8 <= d; i += 8) {
            int s[8];
#pragma unroll
            for (int j = 0; j < 8; ++j) s[j] = csr_src[rs + i + j];
            unsigned short u[8];
#pragma unroll
            for (int j = 0; j < 8; ++j) u[j] = xf8u[(size_t)s[j] * 64 + lane];
#pragma unroll
            for (int j = 0; j < 8; ++j) {
                f32x2 f = __builtin_amdgcn_cvt_pk_f32_fp8((int)u[j], false);
                sl[j] += f.x; sh[j] += f.y;
            }
        }
        for (; i + 4 <= d; i += 4) {
            int s[4];
#pragma unroll
            for (int j = 0; j < 4; ++j) s[j] = csr_src[rs + i + j];
            unsigned short u[4];
#pragma unroll
            for (int j = 0; j < 4; ++j) u[j] = xf8u[(size_t)s[j] * 64 + lane];
#pragma unroll
            for (int j = 0; j < 4; ++j) {
                f32x2 f = __builtin_amdgcn_cvt_pk_f32_fp8((int)u[j], false);
                sl[j] += f.x; sh[j] += f.y;
            }
        }
        for (; i < d; ++i) {
            unsigned short u0 = xf8u[(size_t)csr_src[rs + i] * 64 + lane];
            f32x2 f = __builtin_amdgcn_cvt_pk_f32_fp8((int)u0, false);
            sl[0] += f.x; sh[0] += f.y;
        }
        float ax = ((sl[0] + sl[1]) + (sl[2] + sl[3])) + ((sl[4] + sl[5]) + (sl[6] + sl[7]));
        float ay = ((sh[0] + sh[1]) + (sh[2] + sh[3])) + ((sh[4] + sh[5]) + (sh[6] + sh[7]));
        float inv = 1.0f / fmaxf((float)d, 1.0f);
        unsigned o = ((unsigned)f2bf(ay * inv) << 16) | (unsigned)f2bf(ax * inv);
        ((unsigned*)alds)[row * (LDA / 2) + lane] = o;   // cols 2*lane, 2*lane+1
    }
    __syncthreads();
    // ---- phase 1: h1 tile ----
    int l15 = lane & 15, g = lane >> 4;
    int col0 = wid * 64;
    f32x4 acc[4][4];
#pragma unroll
    for (int mf = 0; mf < 4; ++mf)
#pragma unroll
        for (int nf = 0; nf < 4; ++nf) acc[mf][nf] = (f32x4)(0.0f);
    for (int ks = 0; ks < 8; ++ks) {
        short8 af[4], bfr[4];
#pragma unroll
        for (int mf = 0; mf < 4; ++mf)
            af[mf] = *(const short8*)&alds[(mf * 16 + l15) * LDA + ks * 32 + g * 8];
#pragma unroll
        for (int nf = 0; nf < 4; ++nf)
            bfr[nf] = *(const short8*)&Bp1[((size_t)ks * 256 + col0 + nf * 16 + l15) * 32 + g * 8];
#pragma unroll
        for (int mf = 0; mf < 4; ++mf)
#pragma unroll
            for (int nf = 0; nf < 4; ++nf)
                acc[mf][nf] = __builtin_amdgcn_mfma_f32_16x16x32_bf16(
                    af[mf], bfr[nf], acc[mf][nf], 0, 0, 0);
    }
    float bc[4];
#pragma unroll
    for (int nf = 0; nf < 4; ++nf) bc[nf] = b1[col0 + nf * 16 + l15];
    __syncthreads();   // all alds reads done; reuse alds for h1 tile
#pragma unroll
    for (int mf = 0; mf < 4; ++mf) {
#pragma unroll
        for (int r = 0; r < 4; ++r) {
            int row = mf * 16 + g * 4 + r;
#pragma unroll
            for (int nf = 0; nf < 4; ++nf)
                alds[row * LDA + col0 + nf * 16 + l15] =
                    f2bf(fmaxf(acc[mf][nf][r] + bc[nf], 0.0f));
        }
    }
    __syncthreads();
    // ---- phase 2: zb8/rbufb from LDS h1 tile ----
    int wr = wid >> 1, wc = wid & 1;
    f32x4 acc2[2][3];
#pragma unroll
    for (int mf = 0; mf < 2; ++mf)
#pragma unroll
        for (int nf = 0; nf < 3; ++nf) acc2[mf][nf] = (f32x4)(0.0f);
    for (int ks = 0; ks < 8; ++ks) {
        short8 af[2], bfr[3];
#pragma unroll
        for (int mf = 0; mf < 2; ++mf)
            af[mf] = *(const short8*)&alds[(wr * 32 + mf * 16 + l15) * LDA + ks * 32 + g * 8];
#pragma unroll
        for (int nf = 0; nf < 3; ++nf)
            bfr[nf] = *(const short8*)&Bp2[((size_t)ks * 96 + wc * 48 + nf * 16 + l15) * 32 + g * 8];
#pragma unroll
        for (int mf = 0; mf < 2; ++mf)
#pragma unroll
            for (int nf = 0; nf < 3; ++nf)
                acc2[mf][nf] = __builtin_amdgcn_mfma_f32_16x16x32_bf16(
                    af[mf], bfr[nf], acc2[mf][nf], 0, 0, 0);
    }
#pragma unroll
    for (int nf = 0; nf < 3; ++nf) {
        int col = wc * 48 + nf * 16 + l15;
        float bb = (col >= 48 && col < 89) ? b2[col - 48] : 0.0f;
#pragma unroll
        for (int mf = 0; mf < 2; ++mf) {
            int rowb = n0 + wr * 32 + mf * 16 + g * 4;
#pragma unroll
            for (int r = 0; r < 4; ++r) {
                int row = rowb + r;
                if (row < N) {
                    float v = acc2[mf][nf][r];
                    if (col < 41) {
                        unsigned u = __builtin_amdgcn_cvt_pk_fp8_f32(v, 0.0f, 0, false);
                        zb8[(size_t)row * CPAD + col] = (unsigned char)(u & 0xff);
                    } else if (col >= 48 && col < 89) {
                        rbufb[(size_t)row * CPAD + (col - 48)] = f2bf(v + bb);
                    }
                }
            }
        }
    }
}

// -- gather2+final: 4 nodes/wave (16 lanes each, uint = 4 fp8), unroll-4 -----
__global__ void __launch_bounds__(256)
gather2_kernel(const unsigned* __restrict__ zp8, const unsigned short* __restrict__ rbufb,
               const int* __restrict__ row_start,
               const int* __restrict__ csr_src, float* __restrict__ out, int N) {
    int tid = blockIdx.x * 256 + threadIdx.x;
    int nid = tid >> 4;
    int l = tid & 15;
    if (nid >= N) return;
    int rs = row_start[nid];
    int d = row_start[nid + 1] - rs;
    float a[4][4];
#pragma unroll
    for (int j = 0; j < 4; ++j)
#pragma unroll
        for (int k = 0; k < 4; ++k) a[j][k] = 0.f;
    int i = 0;
    for (; i + 4 <= d; i += 4) {
        int s[4];
#pragma unroll
        for (int j = 0; j < 4; ++j) s[j] = csr_src[rs + i + j];
        unsigned u[4];
#pragma unroll
        for (int j = 0; j < 4; ++j) u[j] = zp8[(size_t)s[j] * 16 + l];
#pragma unroll
        for (int j = 0; j < 4; ++j) {
            f32x2 lo = __builtin_amdgcn_cvt_pk_f32_fp8((int)u[j], false);
            f32x2 hi = __builtin_amdgcn_cvt_pk_f32_fp8((int)u[j], true);
            a[j][0] += lo.x; a[j][1] += lo.y; a[j][2] += hi.x; a[j][3] += hi.y;
        }
    }
    for (; i < d; ++i) {
        unsigned u0 = zp8[(size_t)csr_src[rs + i] * 16 + l];
        f32x2 lo = __builtin_amdgcn_cvt_pk_f32_fp8((int)u0, false);
        f32x2 hi = __builtin_amdgcn_cvt_pk_f32_fp8((int)u0, true);
        a[0][0] += lo.x; a[0][1] += lo.y; a[0][2] += hi.x; a[0][3] += hi.y;
    }
    float inv = 1.0f / fmaxf((float)d, 1.0f);
    ushort4 rb4 = *(const ushort4*)&rbufb[(size_t)nid * CPAD + 4 * l];
    float rbv[4] = {bf2f(rb4.x), bf2f(rb4.y), bf2f(rb4.z), bf2f(rb4.w)};
    float v[4];
#pragma unroll
    for (int k = 0; k < 4; ++k) {
        int col = 4 * l + k;
        v[k] = (col < CLASSES)
             ? ((a[0][k] + a[1][k]) + (a[2][k] + a[3][k])) * inv + rbv[k]
             : -INFINITY;
    }
    float m = fmaxf(fmaxf(v[0], v[1]), fmaxf(v[2], v[3]));
#pragma unroll
    for (int off = 8; off; off >>= 1) m = fmaxf(m, __shfl_xor(m, off, 16));
    float s = 0.f;
#pragma unroll
    for (int k = 0; k < 4; ++k)
        s += (4 * l + k < CLASSES) ? expf(v[k] - m) : 0.0f;
#pragma unroll
    for (int off = 8; off; off >>= 1) s += __shfl_xor(s, off, 16);
    float lse = m + logf(s);
#pragma unroll
    for (int k = 0; k < 4; ++k) {
        int col = 4 * l + k;
        if (col < CLASSES) out[(size_t)nid * CLASSES + col] = v[k] - lse;
    }
}

extern "C" void kernel_launch(void* const* d_in, const int* in_sizes, int n_in,
                              void* d_out, int out_size, void* d_ws, size_t ws_size,
                              hipStream_t stream) {
    const float* x   = (const float*)d_in[0];
    const int*   ei  = (const int*)d_in[1];
    const float* W1l = (const float*)d_in[2];
    const float* W1r = (const float*)d_in[3];
    const float* b1  = (const float*)d_in[4];
    const float* W2l = (const float*)d_in[5];
    const float* W2r = (const float*)d_in[6];
    const float* b2  = (const float*)d_in[7];
    float* out = (float*)d_out;

    int N = in_sizes[0] / IN_FEATS;
    int E = in_sizes[1] / 2;
    const int* src = ei;
    const int* dst = ei + E;

    int NB   = (N + 127) >> BSH;
    int NBLK = (E + CHUNK - 1) / CHUNK;
    int L    = NB * NBLK;

    // ints: [mat L+1][row_start N+1][tmp E (u32)][csr_src E]
    int* ws_i      = (int*)d_ws;
    int* mat       = ws_i;
    int* row_start = ws_i + (size_t)L + 1;
    unsigned* tmp  = (unsigned*)(row_start + (size_t)N + 1);
    int* csr_src   = (int*)(tmp + (size_t)E);
    size_t int_bytes = ((size_t)L + 1 + (size_t)N + 1 + 2 * (size_t)E) * sizeof(int);
    char* p = (char*)d_ws + ((int_bytes + 15) & ~(size_t)15);
    unsigned short* xbf   = (unsigned short*)p;           p += (size_t)N * 128 * 2;
    unsigned*       xf8   = (unsigned*)p;                 p += (size_t)N * 128;
    unsigned short* Bp1   = (unsigned short*)p;           p += 65536 * 2;
    unsigned short* Bp2   = (unsigned short*)p;           p += 24576 * 2;
    unsigned char*  zb8   = (unsigned char*)p;            p += (size_t)N * CPAD;
    unsigned short* rbufb = (unsigned short*)p;

    // ---- CSR construction (no global atomics) ----
    passA_kernel<<<NBLK, 256, 0, stream>>>(dst, mat, E, NB, NBLK);
    scanOne_kernel<<<1, 1024, 0, stream>>>(mat, L);
    passB_kernel<<<NBLK, 256, 0, stream>>>(src, dst, mat, tmp, E, NB, NBLK);
    passC_kernel<<<NB, 256, 0, stream>>>(tmp, mat, row_start, csr_src, E, N, NB, NBLK);

    // ---- conversions + weight pack (one launch; xf8 warm for fused gemm) ----
    long n4 = (long)N * 128 / 4;
    int XB = (int)((n4 + 255) / 256);
    int PB = (65536 + 24576) / 256;
    cvtprep_kernel<<<XB + PB, 256, 0, stream>>>(x, xbf, xf8, n4, XB,
                                                W1l, W1r, W2l, W2r, Bp1, Bp2);

    int gblocks = (N + 63) / 64;
    mgemm_fused_kernel<<<gblocks, 256, 0, stream>>>(
        (const unsigned short*)xf8, xbf, row_start, csr_src,
        Bp1, b1, Bp2, b2, zb8, rbufb, N);
    {
        long long threads = (long long)N * 16;
        gather2_kernel<<<(int)((threads + 255) / 256), 256, 0, stream>>>(
            (const unsigned*)zb8, rbufb, row_start, csr_src, out, N);
    }
}

// Round 12
// 324.757 us; speedup vs baseline: 1.2026x; 1.2026x over previous
//
#include <hip/hip_runtime.h>
#include <math.h>

#define IN_FEATS 128
#define HIDDEN   256
#define CLASSES  41
#define CPAD     64
#define LDA      264    // 256 + 8 pad (bf16 elems)
#define CHUNK    8192   // edges per block in passA/passB
#define BSH      7      // bucket = dst >> 7 (128 nodes per bucket)
#define NBMAX    1024   // max buckets (N <= 131072)

typedef __attribute__((ext_vector_type(8))) short short8;
typedef __attribute__((ext_vector_type(4))) float f32x4;
typedef __attribute__((ext_vector_type(2))) float f32x2;

__device__ __forceinline__ unsigned short f2bf(float f) {
    union { float f; unsigned u; } v; v.f = f;
    unsigned r = v.u + 0x7FFF + ((v.u >> 16) & 1);
    return (unsigned short)(r >> 16);
}
__device__ __forceinline__ float bf2f(unsigned short h) {
    union { unsigned u; float f; } v; v.u = ((unsigned)h) << 16;
    return v.f;
}

// ---- passA: per-chunk LDS histogram over buckets -> mat[b*NBLK + blk] ------
__global__ void __launch_bounds__(256)
passA_kernel(const int* __restrict__ dst, int* __restrict__ mat,
             int E, int NB, int NBLK) {
    __shared__ int hist[NBMAX];
    int blk = blockIdx.x, t = threadIdx.x;
    for (int b = t; b < NB; b += 256) hist[b] = 0;
    __syncthreads();
    int e0 = blk * CHUNK;
    for (int i = t; i < CHUNK; i += 256) {
        int e = e0 + i;
        if (e < E) atomicAdd(&hist[dst[e] >> BSH], 1);
    }
    __syncthreads();
    for (int b = t; b < NB; b += 256) mat[b * NBLK + blk] = hist[b];
}

// ---- scanOne: single-block exclusive scan of mat[0..L] (sentinel at L) -----
__global__ void __launch_bounds__(1024)
scanOne_kernel(int* __restrict__ a, int L) {
    __shared__ int lds[1024];
    __shared__ int carry_s;
    int t = threadIdx.x;
    if (t == 0) carry_s = 0;
    __syncthreads();
    for (int base = 0; base <= L; base += 4096) {
        int v[4];
        int s = 0;
#pragma unroll
        for (int i = 0; i < 4; ++i) {
            int idx = base + t * 4 + i;
            v[i] = (idx < L) ? a[idx] : 0;
            s += v[i];
        }
        lds[t] = s;
        __syncthreads();
        for (int off = 1; off < 1024; off <<= 1) {
            int val = lds[t];
            int add = (t >= off) ? lds[t - off] : 0;
            __syncthreads();
            lds[t] = val + add;
            __syncthreads();
        }
        int run = carry_s + ((t == 0) ? 0 : lds[t - 1]);
        int tot = lds[1023];
#pragma unroll
        for (int i = 0; i < 4; ++i) {
            int idx = base + t * 4 + i;
            if (idx <= L) a[idx] = run;
            run += v[i];
        }
        __syncthreads();
        if (t == 0) carry_s += tot;
        __syncthreads();
    }
}

// ---- passB: scatter packed (src<<7 | dst&127) to bucket-major tmp ----------
__global__ void __launch_bounds__(256)
passB_kernel(const int* __restrict__ src, const int* __restrict__ dst,
             const int* __restrict__ mat, unsigned* __restrict__ tmp,
             int E, int NB, int NBLK) {
    __shared__ int cursor[NBMAX];
    int blk = blockIdx.x, t = threadIdx.x;
    for (int b = t; b < NB; b += 256) cursor[b] = mat[b * NBLK + blk];
    __syncthreads();
    int e0 = blk * CHUNK;
    for (int i = t; i < CHUNK; i += 256) {
        int e = e0 + i;
        if (e < E) {
            int d = dst[e], s = src[e];
            int b = d >> BSH;
            int pos = atomicAdd(&cursor[b], 1);
            tmp[pos] = (unsigned)((s << BSH) | (d & 127));
        }
    }
}

// ---- passC: per-bucket fine CSR: row_start + csr_src -----------------------
__global__ void __launch_bounds__(256)
passC_kernel(const unsigned* __restrict__ tmp, const int* __restrict__ mat,
             int* __restrict__ row_start, int* __restrict__ csr_src,
             int E, int N, int NB, int NBLK) {
    __shared__ int h[128], cur[128], sc[128];
    int b = blockIdx.x, t = threadIdx.x;
    int segBase = mat[b * NBLK];
    int segEnd  = mat[(b + 1) * NBLK];
    int len = segEnd - segBase;
    if (t < 128) h[t] = 0;
    __syncthreads();
    for (int i = t; i < len; i += 256)
        atomicAdd(&h[tmp[segBase + i] & 127], 1);
    __syncthreads();
    if (t < 128) sc[t] = h[t];
    __syncthreads();
    for (int off = 1; off < 128; off <<= 1) {
        int v2 = 0;
        if (t < 128) { v2 = sc[t]; if (t >= off) v2 += sc[t - off]; }
        __syncthreads();
        if (t < 128) sc[t] = v2;
        __syncthreads();
    }
    if (t < 128) {
        int base = segBase + sc[t] - h[t];
        cur[t] = base;
        int n = (b << BSH) + t;
        if (n < N) row_start[n] = base;
    }
    if (b == NB - 1 && t == 0) row_start[N] = segEnd;
    __syncthreads();
    for (int i = t; i < len; i += 256) {
        unsigned w = tmp[segBase + i];
        int pos = atomicAdd(&cur[w & 127], 1);
        csr_src[pos] = (int)(w >> BSH);
    }
}

// ---- cvtprep: x -> bf16 + fp8 (blocks [0,XB)) ; weight pack (rest) ---------
__global__ void __launch_bounds__(256)
cvtprep_kernel(const float* __restrict__ x, unsigned short* __restrict__ xbf,
               unsigned* __restrict__ xf8, long n4, int XB,
               const float* __restrict__ W1l, const float* __restrict__ W1r,
               const float* __restrict__ W2l, const float* __restrict__ W2r,
               unsigned short* __restrict__ Bp1, unsigned short* __restrict__ Bp2) {
    int b = blockIdx.x, t = threadIdx.x;
    if (b < XB) {
        long i = (long)b * 256 + t;
        if (i < n4) {
            float4 v = *(const float4*)(x + i * 4);
            ushort4 o;
            o.x = f2bf(v.x); o.y = f2bf(v.y); o.z = f2bf(v.z); o.w = f2bf(v.w);
            *(ushort4*)(xbf + i * 4) = o;
            unsigned u = __builtin_amdgcn_cvt_pk_fp8_f32(v.x, v.y, 0, false);
            u = __builtin_amdgcn_cvt_pk_fp8_f32(v.z, v.w, u, true);
            xf8[i] = u;
        }
        return;
    }
    int idx = (b - XB) * 256 + t;
    if (idx < 256 * 256) {
        int k = idx >> 8, c = idx & 255;
        float v = (k < 128) ? W1l[k * 256 + c] : W1r[(k - 128) * 256 + c];
        Bp1[((k >> 5) * 256 + c) * 32 + ((k & 31) >> 3) * 8 + (k & 7)] = f2bf(v);
    } else {
        int j = idx - 65536;
        if (j < 256 * 96) {
            int k = j / 96, c = j % 96;
            float v = 0.0f;
            if (c < 41) v = W2l[k * 41 + c];
            else if (c >= 48 && c < 89) v = W2r[k * 41 + (c - 48)];
            Bp2[((k >> 5) * 96 + c) * 32 + ((k & 31) >> 3) * 8 + (k & 7)] = f2bf(v);
        }
    }
}

// ------- gather1: aggm_bf[n] = bf16(mean_{s} xf8[s]), unroll-8 MLP ----------
__global__ void __launch_bounds__(256)
gather1_kernel(const unsigned short* __restrict__ xf8,
               const int* __restrict__ row_start,
               const int* __restrict__ csr_src, unsigned short* __restrict__ aggm,
               int N) {
    int wid = (blockIdx.x * 256 + threadIdx.x) >> 6;
    int lane = threadIdx.x & 63;
    if (wid >= N) return;
    int rs = row_start[wid];
    int d = row_start[wid + 1] - rs;
    float sl[8], sh[8];
#pragma unroll
    for (int j = 0; j < 8; ++j) { sl[j] = 0.f; sh[j] = 0.f; }
    int i = 0;
    for (; i + 8 <= d; i += 8) {
        int s[8];
#pragma unroll
        for (int j = 0; j < 8; ++j) s[j] = csr_src[rs + i + j];
        unsigned short u[8];
#pragma unroll
        for (int j = 0; j < 8; ++j) u[j] = xf8[(size_t)s[j] * 64 + lane];
#pragma unroll
        for (int j = 0; j < 8; ++j) {
            f32x2 f = __builtin_amdgcn_cvt_pk_f32_fp8((int)u[j], false);
            sl[j] += f.x; sh[j] += f.y;
        }
    }
    for (; i + 4 <= d; i += 4) {
        int s[4];
#pragma unroll
        for (int j = 0; j < 4; ++j) s[j] = csr_src[rs + i + j];
        unsigned short u[4];
#pragma unroll
        for (int j = 0; j < 4; ++j) u[j] = xf8[(size_t)s[j] * 64 + lane];
#pragma unroll
        for (int j = 0; j < 4; ++j) {
            f32x2 f = __builtin_amdgcn_cvt_pk_f32_fp8((int)u[j], false);
            sl[j] += f.x; sh[j] += f.y;
        }
    }
    for (; i < d; ++i) {
        unsigned short u0 = xf8[(size_t)csr_src[rs + i] * 64 + lane];
        f32x2 f = __builtin_amdgcn_cvt_pk_f32_fp8((int)u0, false);
        sl[0] += f.x; sh[0] += f.y;
    }
    float ax = ((sl[0] + sl[1]) + (sl[2] + sl[3])) + ((sl[4] + sl[5]) + (sl[6] + sl[7]));
    float ay = ((sh[0] + sh[1]) + (sh[2] + sh[3])) + ((sh[4] + sh[5]) + (sh[6] + sh[7]));
    float inv = 1.0f / fmaxf((float)d, 1.0f);
    unsigned o = ((unsigned)f2bf(ay * inv) << 16) | (unsigned)f2bf(ax * inv);
    ((unsigned*)aggm)[(size_t)wid * 64 + lane] = o;
}

// ---- fused mgemm: h1 = relu([aggm|xbf]@Bp1+b1) kept in LDS;
//      then zb8 = fp8(h1@W2l), rbufb = bf16(h1@W2r + b2) ---------------------
__global__ void __launch_bounds__(256)
mgemm_fused_kernel(const unsigned short* __restrict__ aggm,
                   const unsigned short* __restrict__ xbf,
                   const unsigned short* __restrict__ Bp1, const float* __restrict__ b1,
                   const unsigned short* __restrict__ Bp2, const float* __restrict__ b2,
                   unsigned char* __restrict__ zb8, unsigned short* __restrict__ rbufb,
                   int N) {
    __shared__ __align__(16) unsigned short alds[64 * LDA];
    int n0 = blockIdx.x * 64;
    int t = threadIdx.x;
#pragma unroll
    for (int i = 0; i < 8; ++i) {
        int cid = t + i * 256;
        int row = cid >> 5, c16 = cid & 31;
        int gr = n0 + row;
        uint4 v = make_uint4(0, 0, 0, 0);
        if (gr < N) {
            const unsigned short* srcp = (c16 < 16)
                ? (aggm + (size_t)gr * 128 + c16 * 8)
                : (xbf  + (size_t)gr * 128 + (c16 - 16) * 8);
            v = *(const uint4*)srcp;
        }
        *(uint4*)&alds[row * LDA + c16 * 8] = v;
    }
    __syncthreads();
    int wid = t >> 6, lane = t & 63;
    int l15 = lane & 15, g = lane >> 4;
    int col0 = wid * 64;
    f32x4 acc[4][4];
#pragma unroll
    for (int mf = 0; mf < 4; ++mf)
#pragma unroll
        for (int nf = 0; nf < 4; ++nf) acc[mf][nf] = (f32x4)(0.0f);
    for (int ks = 0; ks < 8; ++ks) {
        short8 af[4], bfr[4];
#pragma unroll
        for (int mf = 0; mf < 4; ++mf)
            af[mf] = *(const short8*)&alds[(mf * 16 + l15) * LDA + ks * 32 + g * 8];
#pragma unroll
        for (int nf = 0; nf < 4; ++nf)
            bfr[nf] = *(const short8*)&Bp1[((size_t)ks * 256 + col0 + nf * 16 + l15) * 32 + g * 8];
#pragma unroll
        for (int mf = 0; mf < 4; ++mf)
#pragma unroll
            for (int nf = 0; nf < 4; ++nf)
                acc[mf][nf] = __builtin_amdgcn_mfma_f32_16x16x32_bf16(
                    af[mf], bfr[nf], acc[mf][nf], 0, 0, 0);
    }
    float bc[4];
#pragma unroll
    for (int nf = 0; nf < 4; ++nf) bc[nf] = b1[col0 + nf * 16 + l15];
    __syncthreads();   // all alds reads done; reuse alds for h1 tile
#pragma unroll
    for (int mf = 0; mf < 4; ++mf) {
#pragma unroll
        for (int r = 0; r < 4; ++r) {
            int row = mf * 16 + g * 4 + r;
#pragma unroll
            for (int nf = 0; nf < 4; ++nf)
                alds[row * LDA + col0 + nf * 16 + l15] =
                    f2bf(fmaxf(acc[mf][nf][r] + bc[nf], 0.0f));
        }
    }
    __syncthreads();
    // ---- phase 2: zb8/rbufb from LDS h1 tile ----
    int wr = wid >> 1, wc = wid & 1;
    f32x4 acc2[2][3];
#pragma unroll
    for (int mf = 0; mf < 2; ++mf)
#pragma unroll
        for (int nf = 0; nf < 3; ++nf) acc2[mf][nf] = (f32x4)(0.0f);
    for (int ks = 0; ks < 8; ++ks) {
        short8 af[2], bfr[3];
#pragma unroll
        for (int mf = 0; mf < 2; ++mf)
            af[mf] = *(const short8*)&alds[(wr * 32 + mf * 16 + l15) * LDA + ks * 32 + g * 8];
#pragma unroll
        for (int nf = 0; nf < 3; ++nf)
            bfr[nf] = *(const short8*)&Bp2[((size_t)ks * 96 + wc * 48 + nf * 16 + l15) * 32 + g * 8];
#pragma unroll
        for (int mf = 0; mf < 2; ++mf)
#pragma unroll
            for (int nf = 0; nf < 3; ++nf)
                acc2[mf][nf] = __builtin_amdgcn_mfma_f32_16x16x32_bf16(
                    af[mf], bfr[nf], acc2[mf][nf], 0, 0, 0);
    }
#pragma unroll
    for (int nf = 0; nf < 3; ++nf) {
        int col = wc * 48 + nf * 16 + l15;
        float bb = (col >= 48 && col < 89) ? b2[col - 48] : 0.0f;
#pragma unroll
        for (int mf = 0; mf < 2; ++mf) {
            int rowb = n0 + wr * 32 + mf * 16 + g * 4;
#pragma unroll
            for (int r = 0; r < 4; ++r) {
                int row = rowb + r;
                if (row < N) {
                    float v = acc2[mf][nf][r];
                    if (col < 41) {
                        unsigned u = __builtin_amdgcn_cvt_pk_fp8_f32(v, 0.0f, 0, false);
                        zb8[(size_t)row * CPAD + col] = (unsigned char)(u & 0xff);
                    } else if (col >= 48 && col < 89) {
                        rbufb[(size_t)row * CPAD + (col - 48)] = f2bf(v + bb);
                    }
                }
            }
        }
    }
}

// -- gather2+final: 4 nodes/wave (16 lanes each, uint = 4 fp8), unroll-4 -----
__global__ void __launch_bounds__(256)
gather2_kernel(const unsigned* __restrict__ zp8, const unsigned short* __restrict__ rbufb,
               const int* __restrict__ row_start,
               const int* __restrict__ csr_src, float* __restrict__ out, int N) {
    int tid = blockIdx.x * 256 + threadIdx.x;
    int nid = tid >> 4;
    int l = tid & 15;
    if (nid >= N) return;
    int rs = row_start[nid];
    int d = row_start[nid + 1] - rs;
    float a[4][4];
#pragma unroll
    for (int j = 0; j < 4; ++j)
#pragma unroll
        for (int k = 0; k < 4; ++k) a[j][k] = 0.f;
    int i = 0;
    for (; i + 4 <= d; i += 4) {
        int s[4];
#pragma unroll
        for (int j = 0; j < 4; ++j) s[j] = csr_src[rs + i + j];
        unsigned u[4];
#pragma unroll
        for (int j = 0; j < 4; ++j) u[j] = zp8[(size_t)s[j] * 16 + l];
#pragma unroll
        for (int j = 0; j < 4; ++j) {
            f32x2 lo = __builtin_amdgcn_cvt_pk_f32_fp8((int)u[j], false);
            f32x2 hi = __builtin_amdgcn_cvt_pk_f32_fp8((int)u[j], true);
            a[j][0] += lo.x; a[j][1] += lo.y; a[j][2] += hi.x; a[j][3] += hi.y;
        }
    }
    for (; i < d; ++i) {
        unsigned u0 = zp8[(size_t)csr_src[rs + i] * 16 + l];
        f32x2 lo = __builtin_amdgcn_cvt_pk_f32_fp8((int)u0, false);
        f32x2 hi = __builtin_amdgcn_cvt_pk_f32_fp8((int)u0, true);
        a[0][0] += lo.x; a[0][1] += lo.y; a[0][2] += hi.x; a[0][3] += hi.y;
    }
    float inv = 1.0f / fmaxf((float)d, 1.0f);
    ushort4 rb4 = *(const ushort4*)&rbufb[(size_t)nid * CPAD + 4 * l];
    float rbv[4] = {bf2f(rb4.x), bf2f(rb4.y), bf2f(rb4.z), bf2f(rb4.w)};
    float v[4];
#pragma unroll
    for (int k = 0; k < 4; ++k) {
        int col = 4 * l + k;
        v[k] = (col < CLASSES)
             ? ((a[0][k] + a[1][k]) + (a[2][k] + a[3][k])) * inv + rbv[k]
             : -INFINITY;
    }
    float m = fmaxf(fmaxf(v[0], v[1]), fmaxf(v[2], v[3]));
#pragma unroll
    for (int off = 8; off; off >>= 1) m = fmaxf(m, __shfl_xor(m, off, 16));
    float s = 0.f;
#pragma unroll
    for (int k = 0; k < 4; ++k)
        s += (4 * l + k < CLASSES) ? expf(v[k] - m) : 0.0f;
#pragma unroll
    for (int off = 8; off; off >>= 1) s += __shfl_xor(s, off, 16);
    float lse = m + logf(s);
#pragma unroll
    for (int k = 0; k < 4; ++k) {
        int col = 4 * l + k;
        if (col < CLASSES) out[(size_t)nid * CLASSES + col] = v[k] - lse;
    }
}

extern "C" void kernel_launch(void* const* d_in, const int* in_sizes, int n_in,
                              void* d_out, int out_size, void* d_ws, size_t ws_size,
                              hipStream_t stream) {
    const float* x   = (const float*)d_in[0];
    const int*   ei  = (const int*)d_in[1];
    const float* W1l = (const float*)d_in[2];
    const float* W1r = (const float*)d_in[3];
    const float* b1  = (const float*)d_in[4];
    const float* W2l = (const float*)d_in[5];
    const float* W2r = (const float*)d_in[6];
    const float* b2  = (const float*)d_in[7];
    float* out = (float*)d_out;

    int N = in_sizes[0] / IN_FEATS;
    int E = in_sizes[1] / 2;
    const int* src = ei;
    const int* dst = ei + E;

    int NB   = (N + 127) >> BSH;
    int NBLK = (E + CHUNK - 1) / CHUNK;
    int L    = NB * NBLK;

    // ints: [mat L+1][row_start N+1][tmp E (u32)][csr_src E]
    int* ws_i      = (int*)d_ws;
    int* mat       = ws_i;
    int* row_start = ws_i + (size_t)L + 1;
    unsigned* tmp  = (unsigned*)(row_start + (size_t)N + 1);
    int* csr_src   = (int*)(tmp + (size_t)E);
    size_t int_bytes = ((size_t)L + 1 + (size_t)N + 1 + 2 * (size_t)E) * sizeof(int);
    char* p = (char*)d_ws + ((int_bytes + 15) & ~(size_t)15);
    unsigned short* xbf   = (unsigned short*)p;           p += (size_t)N * 128 * 2;
    unsigned*       xf8   = (unsigned*)p;                 p += (size_t)N * 128;
    unsigned short* aggm  = (unsigned short*)p;           p += (size_t)N * 128 * 2;
    unsigned short* Bp1   = (unsigned short*)p;           p += 65536 * 2;
    unsigned short* Bp2   = (unsigned short*)p;           p += 24576 * 2;
    unsigned char*  zb8   = (unsigned char*)p;            p += (size_t)N * CPAD;
    unsigned short* rbufb = (unsigned short*)p;

    // ---- CSR construction (no global atomics) ----
    passA_kernel<<<NBLK, 256, 0, stream>>>(dst, mat, E, NB, NBLK);
    scanOne_kernel<<<1, 1024, 0, stream>>>(mat, L);
    passB_kernel<<<NBLK, 256, 0, stream>>>(src, dst, mat, tmp, E, NB, NBLK);
    passC_kernel<<<NB, 256, 0, stream>>>(tmp, mat, row_start, csr_src, E, N, NB, NBLK);

    // ---- conversions + weight pack (one launch; xf8 warm for gather1) ----
    long n4 = (long)N * 128 / 4;
    int XB = (int)((n4 + 255) / 256);
    int PB = (65536 + 24576) / 256;
    cvtprep_kernel<<<XB + PB, 256, 0, stream>>>(x, xbf, xf8, n4, XB,
                                                W1l, W1r, W2l, W2r, Bp1, Bp2);

    {
        long long threads = (long long)N * 64;
        gather1_kernel<<<(int)((threads + 255) / 256), 256, 0, stream>>>(
            (const unsigned short*)xf8, row_start, csr_src, aggm, N);
    }
    int gblocks = (N + 63) / 64;
    mgemm_fused_kernel<<<gblocks, 256, 0, stream>>>(aggm, xbf, Bp1, b1,
                                                    Bp2, b2, zb8, rbufb, N);
    {
        long long threads = (long long)N * 16;
        gather2_kernel<<<(int)((threads + 255) / 256), 256, 0, stream>>>(
            (const unsigned*)zb8, rbufb, row_start, csr_src, out, N);
    }
}

// Round 13
// 210.679 us; speedup vs baseline: 1.8538x; 1.5415x over previous
//
#include <hip/hip_runtime.h>
#include <math.h>

#define IN_FEATS 128
#define HIDDEN   256
#define CLASSES  41
#define CPAD     64
#define SCAN_BLK 1024
#define LDA      264    // 256 + 8 pad (bf16 elems)
#define CHUNK    8192   // edges per block in passA/passB
#define BSH      7      // bucket = dst >> 7 (128 nodes per bucket)
#define NBMAX    1024   // max buckets (N <= 131072)

typedef __attribute__((ext_vector_type(8))) short short8;
typedef __attribute__((ext_vector_type(4))) float f32x4;
typedef __attribute__((ext_vector_type(2))) float f32x2;

__device__ __forceinline__ unsigned short f2bf(float f) {
    union { float f; unsigned u; } v; v.f = f;
    unsigned r = v.u + 0x7FFF + ((v.u >> 16) & 1);
    return (unsigned short)(r >> 16);
}
__device__ __forceinline__ float bf2f(unsigned short h) {
    union { unsigned u; float f; } v; v.u = ((unsigned)h) << 16;
    return v.f;
}

// ---- passA: per-chunk LDS histogram over buckets -> mat[b*NBLK + blk] ------
__global__ void __launch_bounds__(256)
passA_kernel(const int* __restrict__ dst, int* __restrict__ mat,
             int E, int NB, int NBLK) {
    __shared__ int hist[NBMAX];
    int blk = blockIdx.x, t = threadIdx.x;
    for (int b = t; b < NB; b += 256) hist[b] = 0;
    __syncthreads();
    int e0 = blk * CHUNK;
    for (int i = t; i < CHUNK; i += 256) {
        int e = e0 + i;
        if (e < E) atomicAdd(&hist[dst[e] >> BSH], 1);
    }
    __syncthreads();
    for (int b = t; b < NB; b += 256) mat[b * NBLK + blk] = hist[b];
}

// ---- 3-phase exclusive scan of mat[0..L] (sentinel at L) -------------------
__global__ void __launch_bounds__(256)
scanM1_kernel(int* __restrict__ a, int* __restrict__ bs, int L) {
    __shared__ int lds[256];
    int base = blockIdx.x * SCAN_BLK;
    int t = threadIdx.x;
    int v[4];
    int s = 0;
#pragma unroll
    for (int i = 0; i < 4; ++i) {
        int idx = base + t * 4 + i;
        v[i] = (idx < L) ? a[idx] : 0;
        s += v[i];
    }
    lds[t] = s;
    __syncthreads();
    for (int off = 1; off < 256; off <<= 1) {
        int val = lds[t];
        int add = (t >= off) ? lds[t - off] : 0;
        __syncthreads();
        lds[t] = val + add;
        __syncthreads();
    }
    if (t == 255) bs[blockIdx.x] = lds[255];
    int run = (t == 0) ? 0 : lds[t - 1];
#pragma unroll
    for (int i = 0; i < 4; ++i) {
        int idx = base + t * 4 + i;
        if (idx <= L) a[idx] = run;
        run += v[i];
    }
}

__global__ void __launch_bounds__(256)
scan2_kernel(int* __restrict__ bs, int nb) {
    __shared__ int lds[256];
    int t = threadIdx.x;
    lds[t] = (t < nb) ? bs[t] : 0;
    __syncthreads();
    for (int off = 1; off < 256; off <<= 1) {
        int val = lds[t];
        int add = (t >= off) ? lds[t - off] : 0;
        __syncthreads();
        lds[t] = val + add;
        __syncthreads();
    }
    if (t < nb) bs[t] = (t == 0) ? 0 : lds[t - 1];
}

__global__ void __launch_bounds__(256)
scanM3_kernel(int* __restrict__ a, const int* __restrict__ bs, int L) {
    int idx = blockIdx.x * 256 + threadIdx.x;
    if (idx <= L) a[idx] += bs[idx / SCAN_BLK];
}

// ---- passB: scatter packed (src<<7 | dst&127) to bucket-major tmp ----------
__global__ void __launch_bounds__(256)
passB_kernel(const int* __restrict__ src, const int* __restrict__ dst,
             const int* __restrict__ mat, unsigned* __restrict__ tmp,
             int E, int NB, int NBLK) {
    __shared__ int cursor[NBMAX];
    int blk = blockIdx.x, t = threadIdx.x;
    for (int b = t; b < NB; b += 256) cursor[b] = mat[b * NBLK + blk];
    __syncthreads();
    int e0 = blk * CHUNK;
    for (int i = t; i < CHUNK; i += 256) {
        int e = e0 + i;
        if (e < E) {
            int d = dst[e], s = src[e];
            int b = d >> BSH;
            int pos = atomicAdd(&cursor[b], 1);
            tmp[pos] = (unsigned)((s << BSH) | (d & 127));
        }
    }
}

// ---- passC: per-bucket fine CSR: row_start + csr_src -----------------------
__global__ void __launch_bounds__(256)
passC_kernel(const unsigned* __restrict__ tmp, const int* __restrict__ mat,
             int* __restrict__ row_start, int* __restrict__ csr_src,
             int E, int N, int NB, int NBLK) {
    __shared__ int h[128], cur[128], sc[128];
    int b = blockIdx.x, t = threadIdx.x;
    int segBase = mat[b * NBLK];
    int segEnd  = mat[(b + 1) * NBLK];
    int len = segEnd - segBase;
    if (t < 128) h[t] = 0;
    __syncthreads();
    for (int i = t; i < len; i += 256)
        atomicAdd(&h[tmp[segBase + i] & 127], 1);
    __syncthreads();
    if (t < 128) sc[t] = h[t];
    __syncthreads();
    for (int off = 1; off < 128; off <<= 1) {
        int v2 = 0;
        if (t < 128) { v2 = sc[t]; if (t >= off) v2 += sc[t - off]; }
        __syncthreads();
        if (t < 128) sc[t] = v2;
        __syncthreads();
    }
    if (t < 128) {
        int base = segBase + sc[t] - h[t];
        cur[t] = base;
        int n = (b << BSH) + t;
        if (n < N) row_start[n] = base;
    }
    if (b == NB - 1 && t == 0) row_start[N] = segEnd;
    __syncthreads();
    for (int i = t; i < len; i += 256) {
        unsigned w = tmp[segBase + i];
        int pos = atomicAdd(&cur[w & 127], 1);
        csr_src[pos] = (int)(w >> BSH);
    }
}

// ---- cvtprep: x -> bf16 + fp8 (blocks [0,XB)) ; weight pack (rest) ---------
__global__ void __launch_bounds__(256)
cvtprep_kernel(const float* __restrict__ x, unsigned short* __restrict__ xbf,
               unsigned* __restrict__ xf8, long n4, int XB,
               const float* __restrict__ W1l, const float* __restrict__ W1r,
               const float* __restrict__ W2l, const float* __restrict__ W2r,
               unsigned short* __restrict__ Bp1, unsigned short* __restrict__ Bp2) {
    int b = blockIdx.x, t = threadIdx.x;
    if (b < XB) {
        long i = (long)b * 256 + t;
        if (i < n4) {
            float4 v = *(const float4*)(x + i * 4);
            ushort4 o;
            o.x = f2bf(v.x); o.y = f2bf(v.y); o.z = f2bf(v.z); o.w = f2bf(v.w);
            *(ushort4*)(xbf + i * 4) = o;
            unsigned u = __builtin_amdgcn_cvt_pk_fp8_f32(v.x, v.y, 0, false);
            u = __builtin_amdgcn_cvt_pk_fp8_f32(v.z, v.w, u, true);
            xf8[i] = u;
        }
        return;
    }
    int idx = (b - XB) * 256 + t;
    if (idx < 256 * 256) {
        int k = idx >> 8, c = idx & 255;
        float v = (k < 128) ? W1l[k * 256 + c] : W1r[(k - 128) * 256 + c];
        Bp1[((k >> 5) * 256 + c) * 32 + ((k & 31) >> 3) * 8 + (k & 7)] = f2bf(v);
    } else {
        int j = idx - 65536;
        if (j < 256 * 96) {
            int k = j / 96, c = j % 96;
            float v = 0.0f;
            if (c < 41) v = W2l[k * 41 + c];
            else if (c >= 48 && c < 89) v = W2r[k * 41 + (c - 48)];
            Bp2[((k >> 5) * 96 + c) * 32 + ((k & 31) >> 3) * 8 + (k & 7)] = f2bf(v);
        }
    }
}

// ------- gather1: aggm_bf[n] = bf16(mean_{s} xf8[s]), unroll-8 MLP ----------
__global__ void __launch_bounds__(256)
gather1_kernel(const unsigned short* __restrict__ xf8,
               const int* __restrict__ row_start,
               const int* __restrict__ csr_src, unsigned short* __restrict__ aggm,
               int N) {
    int wid = (blockIdx.x * 256 + threadIdx.x) >> 6;
    int lane = threadIdx.x & 63;
    if (wid >= N) return;
    int rs = row_start[wid];
    int d = row_start[wid + 1] - rs;
    float sl[8], sh[8];
#pragma unroll
    for (int j = 0; j < 8; ++j) { sl[j] = 0.f; sh[j] = 0.f; }
    int i = 0;
    for (; i + 8 <= d; i += 8) {
        int s[8];
#pragma unroll
        for (int j = 0; j < 8; ++j) s[j] = csr_src[rs + i + j];
        unsigned short u[8];
#pragma unroll
        for (int j = 0; j < 8; ++j) u[j] = xf8[(size_t)s[j] * 64 + lane];
#pragma unroll
        for (int j = 0; j < 8; ++j) {
            f32x2 f = __builtin_amdgcn_cvt_pk_f32_fp8((int)u[j], false);
            sl[j] += f.x; sh[j] += f.y;
        }
    }
    for (; i + 4 <= d; i += 4) {
        int s[4];
#pragma unroll
        for (int j = 0; j < 4; ++j) s[j] = csr_src[rs + i + j];
        unsigned short u[4];
#pragma unroll
        for (int j = 0; j < 4; ++j) u[j] = xf8[(size_t)s[j] * 64 + lane];
#pragma unroll
        for (int j = 0; j < 4; ++j) {
            f32x2 f = __builtin_amdgcn_cvt_pk_f32_fp8((int)u[j], false);
            sl[j] += f.x; sh[j] += f.y;
        }
    }
    for (; i < d; ++i) {
        unsigned short u0 = xf8[(size_t)csr_src[rs + i] * 64 + lane];
        f32x2 f = __builtin_amdgcn_cvt_pk_f32_fp8((int)u0, false);
        sl[0] += f.x; sh[0] += f.y;
    }
    float ax = ((sl[0] + sl[1]) + (sl[2] + sl[3])) + ((sl[4] + sl[5]) + (sl[6] + sl[7]));
    float ay = ((sh[0] + sh[1]) + (sh[2] + sh[3])) + ((sh[4] + sh[5]) + (sh[6] + sh[7]));
    float inv = 1.0f / fmaxf((float)d, 1.0f);
    unsigned o = ((unsigned)f2bf(ay * inv) << 16) | (unsigned)f2bf(ax * inv);
    ((unsigned*)aggm)[(size_t)wid * 64 + lane] = o;
}

// ---- fused mgemm: h1 = relu([aggm|xbf]@Bp1+b1) kept in LDS;
//      then zb8 = fp8(h1@W2l), rbufb = bf16(h1@W2r + b2) ---------------------
__global__ void __launch_bounds__(256)
mgemm_fused_kernel(const unsigned short* __restrict__ aggm,
                   const unsigned short* __restrict__ xbf,
                   const unsigned short* __restrict__ Bp1, const float* __restrict__ b1,
                   const unsigned short* __restrict__ Bp2, const float* __restrict__ b2,
                   unsigned char* __restrict__ zb8, unsigned short* __restrict__ rbufb,
                   int N) {
    __shared__ __align__(16) unsigned short alds[64 * LDA];
    int n0 = blockIdx.x * 64;
    int t = threadIdx.x;
#pragma unroll
    for (int i = 0; i < 8; ++i) {
        int cid = t + i * 256;
        int row = cid >> 5, c16 = cid & 31;
        int gr = n0 + row;
        uint4 v = make_uint4(0, 0, 0, 0);
        if (gr < N) {
            const unsigned short* srcp = (c16 < 16)
                ? (aggm + (size_t)gr * 128 + c16 * 8)
                : (xbf  + (size_t)gr * 128 + (c16 - 16) * 8);
            v = *(const uint4*)srcp;
        }
        *(uint4*)&alds[row * LDA + c16 * 8] = v;
    }
    __syncthreads();
    int wid = t >> 6, lane = t & 63;
    int l15 = lane & 15, g = lane >> 4;
    int col0 = wid * 64;
    f32x4 acc[4][4];
#pragma unroll
    for (int mf = 0; mf < 4; ++mf)
#pragma unroll
        for (int nf = 0; nf < 4; ++nf) acc[mf][nf] = (f32x4)(0.0f);
    for (int ks = 0; ks < 8; ++ks) {
        short8 af[4], bfr[4];
#pragma unroll
        for (int mf = 0; mf < 4; ++mf)
            af[mf] = *(const short8*)&alds[(mf * 16 + l15) * LDA + ks * 32 + g * 8];
#pragma unroll
        for (int nf = 0; nf < 4; ++nf)
            bfr[nf] = *(const short8*)&Bp1[((size_t)ks * 256 + col0 + nf * 16 + l15) * 32 + g * 8];
#pragma unroll
        for (int mf = 0; mf < 4; ++mf)
#pragma unroll
            for (int nf = 0; nf < 4; ++nf)
                acc[mf][nf] = __builtin_amdgcn_mfma_f32_16x16x32_bf16(
                    af[mf], bfr[nf], acc[mf][nf], 0, 0, 0);
    }
    float bc[4];
#pragma unroll
    for (int nf = 0; nf < 4; ++nf) bc[nf] = b1[col0 + nf * 16 + l15];
    __syncthreads();   // all alds reads done; reuse alds for h1 tile
#pragma unroll
    for (int mf = 0; mf < 4; ++mf) {
#pragma unroll
        for (int r = 0; r < 4; ++r) {
            int row = mf * 16 + g * 4 + r;
#pragma unroll
            for (int nf = 0; nf < 4; ++nf)
                alds[row * LDA + col0 + nf * 16 + l15] =
                    f2bf(fmaxf(acc[mf][nf][r] + bc[nf], 0.0f));
        }
    }
    __syncthreads();
    // ---- phase 2: zb8/rbufb from LDS h1 tile ----
    int wr = wid >> 1, wc = wid & 1;
    f32x4 acc2[2][3];
#pragma unroll
    for (int mf = 0; mf < 2; ++mf)
#pragma unroll
        for (int nf = 0; nf < 3; ++nf) acc2[mf][nf] = (f32x4)(0.0f);
    for (int ks = 0; ks < 8; ++ks) {
        short8 af[2], bfr[3];
#pragma unroll
        for (int mf = 0; mf < 2; ++mf)
            af[mf] = *(const short8*)&alds[(wr * 32 + mf * 16 + l15) * LDA + ks * 32 + g * 8];
#pragma unroll
        for (int nf = 0; nf < 3; ++nf)
            bfr[nf] = *(const short8*)&Bp2[((size_t)ks * 96 + wc * 48 + nf * 16 + l15) * 32 + g * 8];
#pragma unroll
        for (int mf = 0; mf < 2; ++mf)
#pragma unroll
            for (int nf = 0; nf < 3; ++nf)
                acc2[mf][nf] = __builtin_amdgcn_mfma_f32_16x16x32_bf16(
                    af[mf], bfr[nf], acc2[mf][nf], 0, 0, 0);
    }
#pragma unroll
    for (int nf = 0; nf < 3; ++nf) {
        int col = wc * 48 + nf * 16 + l15;
        float bb = (col >= 48 && col < 89) ? b2[col - 48] : 0.0f;
#pragma unroll
        for (int mf = 0; mf < 2; ++mf) {
            int rowb = n0 + wr * 32 + mf * 16 + g * 4;
#pragma unroll
            for (int r = 0; r < 4; ++r) {
                int row = rowb + r;
                if (row < N) {
                    float v = acc2[mf][nf][r];
                    if (col < 41) {
                        unsigned u = __builtin_amdgcn_cvt_pk_fp8_f32(v, 0.0f, 0, false);
                        zb8[(size_t)row * CPAD + col] = (unsigned char)(u & 0xff);
                    } else if (col >= 48 && col < 89) {
                        rbufb[(size_t)row * CPAD + (col - 48)] = f2bf(v + bb);
                    }
                }
            }
        }
    }
}

// -- gather2+final: 4 nodes/wave (16 lanes each, uint = 4 fp8), unroll-4 -----
__global__ void __launch_bounds__(256)
gather2_kernel(const unsigned* __restrict__ zp8, const unsigned short* __restrict__ rbufb,
               const int* __restrict__ row_start,
               const int* __restrict__ csr_src, float* __restrict__ out, int N) {
    int tid = blockIdx.x * 256 + threadIdx.x;
    int nid = tid >> 4;
    int l = tid & 15;
    if (nid >= N) return;
    int rs = row_start[nid];
    int d = row_start[nid + 1] - rs;
    float a[4][4];
#pragma unroll
    for (int j = 0; j < 4; ++j)
#pragma unroll
        for (int k = 0; k < 4; ++k) a[j][k] = 0.f;
    int i = 0;
    for (; i + 4 <= d; i += 4) {
        int s[4];
#pragma unroll
        for (int j = 0; j < 4; ++j) s[j] = csr_src[rs + i + j];
        unsigned u[4];
#pragma unroll
        for (int j = 0; j < 4; ++j) u[j] = zp8[(size_t)s[j] * 16 + l];
#pragma unroll
        for (int j = 0; j < 4; ++j) {
            f32x2 lo = __builtin_amdgcn_cvt_pk_f32_fp8((int)u[j], false);
            f32x2 hi = __builtin_amdgcn_cvt_pk_f32_fp8((int)u[j], true);
            a[j][0] += lo.x; a[j][1] += lo.y; a[j][2] += hi.x; a[j][3] += hi.y;
        }
    }
    for (; i < d; ++i) {
        unsigned u0 = zp8[(size_t)csr_src[rs + i] * 16 + l];
        f32x2 lo = __builtin_amdgcn_cvt_pk_f32_fp8((int)u0, false);
        f32x2 hi = __builtin_amdgcn_cvt_pk_f32_fp8((int)u0, true);
        a[0][0] += lo.x; a[0][1] += lo.y; a[0][2] += hi.x; a[0][3] += hi.y;
    }
    float inv = 1.0f / fmaxf((float)d, 1.0f);
    ushort4 rb4 = *(const ushort4*)&rbufb[(size_t)nid * CPAD + 4 * l];
    float rbv[4] = {bf2f(rb4.x), bf2f(rb4.y), bf2f(rb4.z), bf2f(rb4.w)};
    float v[4];
#pragma unroll
    for (int k = 0; k < 4; ++k) {
        int col = 4 * l + k;
        v[k] = (col < CLASSES)
             ? ((a[0][k] + a[1][k]) + (a[2][k] + a[3][k])) * inv + rbv[k]
             : -INFINITY;
    }
    float m = fmaxf(fmaxf(v[0], v[1]), fmaxf(v[2], v[3]));
#pragma unroll
    for (int off = 8; off; off >>= 1) m = fmaxf(m, __shfl_xor(m, off, 16));
    float s = 0.f;
#pragma unroll
    for (int k = 0; k < 4; ++k)
        s += (4 * l + k < CLASSES) ? expf(v[k] - m) : 0.0f;
#pragma unroll
    for (int off = 8; off; off >>= 1) s += __shfl_xor(s, off, 16);
    float lse = m + logf(s);
#pragma unroll
    for (int k = 0; k < 4; ++k) {
        int col = 4 * l + k;
        if (col < CLASSES) out[(size_t)nid * CLASSES + col] = v[k] - lse;
    }
}

extern "C" void kernel_launch(void* const* d_in, const int* in_sizes, int n_in,
                              void* d_out, int out_size, void* d_ws, size_t ws_size,
                              hipStream_t stream) {
    const float* x   = (const float*)d_in[0];
    const int*   ei  = (const int*)d_in[1];
    const float* W1l = (const float*)d_in[2];
    const float* W1r = (const float*)d_in[3];
    const float* b1  = (const float*)d_in[4];
    const float* W2l = (const float*)d_in[5];
    const float* W2r = (const float*)d_in[6];
    const float* b2  = (const float*)d_in[7];
    float* out = (float*)d_out;

    int N = in_sizes[0] / IN_FEATS;
    int E = in_sizes[1] / 2;
    const int* src = ei;
    const int* dst = ei + E;

    int NB   = (N + 127) >> BSH;
    int NBLK = (E + CHUNK - 1) / CHUNK;
    int L    = NB * NBLK;

    // ints: [mat L+1][blk_sums 256][row_start N+1][tmp E (u32)][csr_src E]
    int* ws_i      = (int*)d_ws;
    int* mat       = ws_i;
    int* blk_sums  = ws_i + (size_t)L + 1;
    int* row_start = blk_sums + 256;
    unsigned* tmp  = (unsigned*)(row_start + (size_t)N + 1);
    int* csr_src   = (int*)(tmp + (size_t)E);
    size_t int_bytes = ((size_t)L + 1 + 256 + (size_t)N + 1 + 2 * (size_t)E) * sizeof(int);
    char* p = (char*)d_ws + ((int_bytes + 15) & ~(size_t)15);
    unsigned short* xbf   = (unsigned short*)p;           p += (size_t)N * 128 * 2;
    unsigned*       xf8   = (unsigned*)p;                 p += (size_t)N * 128;
    unsigned short* aggm  = (unsigned short*)p;           p += (size_t)N * 128 * 2;
    unsigned short* Bp1   = (unsigned short*)p;           p += 65536 * 2;
    unsigned short* Bp2   = (unsigned short*)p;           p += 24576 * 2;
    unsigned char*  zb8   = (unsigned char*)p;            p += (size_t)N * CPAD;
    unsigned short* rbufb = (unsigned short*)p;

    // ---- CSR construction (no global atomics) ----
    passA_kernel<<<NBLK, 256, 0, stream>>>(dst, mat, E, NB, NBLK);
    int nscanM = (L + 1 + SCAN_BLK - 1) / SCAN_BLK;
    scanM1_kernel<<<nscanM, 256, 0, stream>>>(mat, blk_sums, L);
    scan2_kernel<<<1, 256, 0, stream>>>(blk_sums, nscanM);
    scanM3_kernel<<<(L + 1 + 255) / 256, 256, 0, stream>>>(mat, blk_sums, L);
    passB_kernel<<<NBLK, 256, 0, stream>>>(src, dst, mat, tmp, E, NB, NBLK);
    passC_kernel<<<NB, 256, 0, stream>>>(tmp, mat, row_start, csr_src, E, N, NB, NBLK);

    // ---- conversions + weight pack (one launch; xf8 warm for gather1) ----
    long n4 = (long)N * 128 / 4;
    int XB = (int)((n4 + 255) / 256);
    int PB = (65536 + 24576) / 256;
    cvtprep_kernel<<<XB + PB, 256, 0, stream>>>(x, xbf, xf8, n4, XB,
                                                W1l, W1r, W2l, W2r, Bp1, Bp2);

    {
        long long threads = (long long)N * 64;
        gather1_kernel<<<(int)((threads + 255) / 256), 256, 0, stream>>>(
            (const unsigned short*)xf8, row_start, csr_src, aggm, N);
    }
    int gblocks = (N + 63) / 64;
    mgemm_fused_kernel<<<gblocks, 256, 0, stream>>>(aggm, xbf, Bp1, b1,
                                                    Bp2, b2, zb8, rbufb, N);
    {
        long long threads = (long long)N * 16;
        gather2_kernel<<<(int)((threads + 255) / 256), 256, 0, stream>>>(
            (const unsigned*)zb8, rbufb, row_start, csr_src, out, N);
    }
}

// Round 14
// 205.338 us; speedup vs baseline: 1.9020x; 1.0260x over previous
//
#include <hip/hip_runtime.h>
#include <math.h>

#define IN_FEATS 128
#define HIDDEN   256
#define CLASSES  41
#define CPAD     64
#define SCAN_BLK 1024
#define LDA      264    // 256 + 8 pad (bf16 elems)
#define CHUNK    8192   // edges per block in passA/passB
#define BSH      7      // bucket = dst >> 7 (128 nodes per bucket)
#define NBMAX    1024   // max buckets (N <= 131072)

typedef __attribute__((ext_vector_type(8))) short short8;
typedef __attribute__((ext_vector_type(4))) float f32x4;
typedef __attribute__((ext_vector_type(2))) float f32x2;

__device__ __forceinline__ unsigned short f2bf(float f) {
    union { float f; unsigned u; } v; v.f = f;
    unsigned r = v.u + 0x7FFF + ((v.u >> 16) & 1);
    return (unsigned short)(r >> 16);
}
__device__ __forceinline__ float bf2f(unsigned short h) {
    union { unsigned u; float f; } v; v.u = ((unsigned)h) << 16;
    return v.f;
}

// ---- passA: per-chunk LDS histogram over buckets -> mat[b*NBLK + blk] ------
__global__ void __launch_bounds__(256)
passA_kernel(const int* __restrict__ dst, int* __restrict__ mat,
             int E, int NB, int NBLK) {
    __shared__ int hist[NBMAX];
    int blk = blockIdx.x, t = threadIdx.x;
    for (int b = t; b < NB; b += 256) hist[b] = 0;
    __syncthreads();
    int e0 = blk * CHUNK;
    for (int i = t; i < CHUNK; i += 256) {
        int e = e0 + i;
        if (e < E) atomicAdd(&hist[dst[e] >> BSH], 1);
    }
    __syncthreads();
    for (int b = t; b < NB; b += 256) mat[b * NBLK + blk] = hist[b];
}

// ---- 3-phase exclusive scan of mat[0..L] (sentinel at L) -------------------
__global__ void __launch_bounds__(256)
scanM1_kernel(int* __restrict__ a, int* __restrict__ bs, int L) {
    __shared__ int lds[256];
    int base = blockIdx.x * SCAN_BLK;
    int t = threadIdx.x;
    int v[4];
    int s = 0;
#pragma unroll
    for (int i = 0; i < 4; ++i) {
        int idx = base + t * 4 + i;
        v[i] = (idx < L) ? a[idx] : 0;
        s += v[i];
    }
    lds[t] = s;
    __syncthreads();
    for (int off = 1; off < 256; off <<= 1) {
        int val = lds[t];
        int add = (t >= off) ? lds[t - off] : 0;
        __syncthreads();
        lds[t] = val + add;
        __syncthreads();
    }
    if (t == 255) bs[blockIdx.x] = lds[255];
    int run = (t == 0) ? 0 : lds[t - 1];
#pragma unroll
    for (int i = 0; i < 4; ++i) {
        int idx = base + t * 4 + i;
        if (idx <= L) a[idx] = run;
        run += v[i];
    }
}

__global__ void __launch_bounds__(256)
scan2_kernel(int* __restrict__ bs, int nb) {
    __shared__ int lds[256];
    int t = threadIdx.x;
    lds[t] = (t < nb) ? bs[t] : 0;
    __syncthreads();
    for (int off = 1; off < 256; off <<= 1) {
        int val = lds[t];
        int add = (t >= off) ? lds[t - off] : 0;
        __syncthreads();
        lds[t] = val + add;
        __syncthreads();
    }
    if (t < nb) bs[t] = (t == 0) ? 0 : lds[t - 1];
}

__global__ void __launch_bounds__(256)
scanM3_kernel(int* __restrict__ a, const int* __restrict__ bs, int L) {
    int idx = blockIdx.x * 256 + threadIdx.x;
    if (idx <= L) a[idx] += bs[idx / SCAN_BLK];
}

// ---- passB: scatter packed (src<<7 | dst&127) to bucket-major tmp ----------
__global__ void __launch_bounds__(256)
passB_kernel(const int* __restrict__ src, const int* __restrict__ dst,
             const int* __restrict__ mat, unsigned* __restrict__ tmp,
             int E, int NB, int NBLK) {
    __shared__ int cursor[NBMAX];
    int blk = blockIdx.x, t = threadIdx.x;
    for (int b = t; b < NB; b += 256) cursor[b] = mat[b * NBLK + blk];
    __syncthreads();
    int e0 = blk * CHUNK;
    for (int i = t; i < CHUNK; i += 256) {
        int e = e0 + i;
        if (e < E) {
            int d = dst[e], s = src[e];
            int b = d >> BSH;
            int pos = atomicAdd(&cursor[b], 1);
            tmp[pos] = (unsigned)((s << BSH) | (d & 127));
        }
    }
}

// ---- passC: per-bucket fine CSR: row_start + csr_src -----------------------
__global__ void __launch_bounds__(256)
passC_kernel(const unsigned* __restrict__ tmp, const int* __restrict__ mat,
             int* __restrict__ row_start, int* __restrict__ csr_src,
             int E, int N, int NB, int NBLK) {
    __shared__ int h[128], cur[128], sc[128];
    int b = blockIdx.x, t = threadIdx.x;
    int segBase = mat[b * NBLK];
    int segEnd  = mat[(b + 1) * NBLK];
    int len = segEnd - segBase;
    if (t < 128) h[t] = 0;
    __syncthreads();
    for (int i = t; i < len; i += 256)
        atomicAdd(&h[tmp[segBase + i] & 127], 1);
    __syncthreads();
    if (t < 128) sc[t] = h[t];
    __syncthreads();
    for (int off = 1; off < 128; off <<= 1) {
        int v2 = 0;
        if (t < 128) { v2 = sc[t]; if (t >= off) v2 += sc[t - off]; }
        __syncthreads();
        if (t < 128) sc[t] = v2;
        __syncthreads();
    }
    if (t < 128) {
        int base = segBase + sc[t] - h[t];
        cur[t] = base;
        int n = (b << BSH) + t;
        if (n < N) row_start[n] = base;
    }
    if (b == NB - 1 && t == 0) row_start[N] = segEnd;
    __syncthreads();
    for (int i = t; i < len; i += 256) {
        unsigned w = tmp[segBase + i];
        int pos = atomicAdd(&cur[w & 127], 1);
        csr_src[pos] = (int)(w >> BSH);
    }
}

// ---- cvtprep: x -> fp8 (blocks [0,XB)) ; weight pack (rest) ----------------
__global__ void __launch_bounds__(256)
cvtprep_kernel(const float* __restrict__ x, unsigned* __restrict__ xf8,
               long n4, int XB,
               const float* __restrict__ W1l, const float* __restrict__ W1r,
               const float* __restrict__ W2l, const float* __restrict__ W2r,
               unsigned short* __restrict__ Bp1, unsigned short* __restrict__ Bp2) {
    int b = blockIdx.x, t = threadIdx.x;
    if (b < XB) {
        long i = (long)b * 256 + t;
        if (i < n4) {
            float4 v = *(const float4*)(x + i * 4);
            unsigned u = __builtin_amdgcn_cvt_pk_fp8_f32(v.x, v.y, 0, false);
            u = __builtin_amdgcn_cvt_pk_fp8_f32(v.z, v.w, u, true);
            xf8[i] = u;
        }
        return;
    }
    int idx = (b - XB) * 256 + t;
    if (idx < 256 * 256) {
        int k = idx >> 8, c = idx & 255;
        float v = (k < 128) ? W1l[k * 256 + c] : W1r[(k - 128) * 256 + c];
        Bp1[((k >> 5) * 256 + c) * 32 + ((k & 31) >> 3) * 8 + (k & 7)] = f2bf(v);
    } else {
        int j = idx - 65536;
        if (j < 256 * 96) {
            int k = j / 96, c = j % 96;
            float v = 0.0f;
            if (c < 41) v = W2l[k * 41 + c];
            else if (c >= 48 && c < 89) v = W2r[k * 41 + (c - 48)];
            Bp2[((k >> 5) * 96 + c) * 32 + ((k & 31) >> 3) * 8 + (k & 7)] = f2bf(v);
        }
    }
}

// ------- gather1: aggm_bf[n] = bf16(mean_{s} xf8[s]), unroll-8 MLP ----------
__global__ void __launch_bounds__(256)
gather1_kernel(const unsigned short* __restrict__ xf8,
               const int* __restrict__ row_start,
               const int* __restrict__ csr_src, unsigned short* __restrict__ aggm,
               int N) {
    int wid = (blockIdx.x * 256 + threadIdx.x) >> 6;
    int lane = threadIdx.x & 63;
    if (wid >= N) return;
    int rs = row_start[wid];
    int d = row_start[wid + 1] - rs;
    float sl[8], sh[8];
#pragma unroll
    for (int j = 0; j < 8; ++j) { sl[j] = 0.f; sh[j] = 0.f; }
    int i = 0;
    for (; i + 8 <= d; i += 8) {
        int s[8];
#pragma unroll
        for (int j = 0; j < 8; ++j) s[j] = csr_src[rs + i + j];
        unsigned short u[8];
#pragma unroll
        for (int j = 0; j < 8; ++j) u[j] = xf8[(size_t)s[j] * 64 + lane];
#pragma unroll
        for (int j = 0; j < 8; ++j) {
            f32x2 f = __builtin_amdgcn_cvt_pk_f32_fp8((int)u[j], false);
            sl[j] += f.x; sh[j] += f.y;
        }
    }
    for (; i + 4 <= d; i += 4) {
        int s[4];
#pragma unroll
        for (int j = 0; j < 4; ++j) s[j] = csr_src[rs + i + j];
        unsigned short u[4];
#pragma unroll
        for (int j = 0; j < 4; ++j) u[j] = xf8[(size_t)s[j] * 64 + lane];
#pragma unroll
        for (int j = 0; j < 4; ++j) {
            f32x2 f = __builtin_amdgcn_cvt_pk_f32_fp8((int)u[j], false);
            sl[j] += f.x; sh[j] += f.y;
        }
    }
    for (; i < d; ++i) {
        unsigned short u0 = xf8[(size_t)csr_src[rs + i] * 64 + lane];
        f32x2 f = __builtin_amdgcn_cvt_pk_f32_fp8((int)u0, false);
        sl[0] += f.x; sh[0] += f.y;
    }
    float ax = ((sl[0] + sl[1]) + (sl[2] + sl[3])) + ((sl[4] + sl[5]) + (sl[6] + sl[7]));
    float ay = ((sh[0] + sh[1]) + (sh[2] + sh[3])) + ((sh[4] + sh[5]) + (sh[6] + sh[7]));
    float inv = 1.0f / fmaxf((float)d, 1.0f);
    unsigned o = ((unsigned)f2bf(ay * inv) << 16) | (unsigned)f2bf(ax * inv);
    ((unsigned*)aggm)[(size_t)wid * 64 + lane] = o;
}

// ---- fused mgemm: stage [aggm bf16 | xf8->bf16] in LDS; h1 = relu(A@Bp1+b1)
//      kept in LDS; then zb8 = fp8(h1@W2l), rbufb = bf16(h1@W2r + b2) --------
__global__ void __launch_bounds__(256)
mgemm_fused_kernel(const unsigned short* __restrict__ aggm,
                   const unsigned char* __restrict__ xf8b,
                   const unsigned short* __restrict__ Bp1, const float* __restrict__ b1,
                   const unsigned short* __restrict__ Bp2, const float* __restrict__ b2,
                   unsigned char* __restrict__ zb8, unsigned short* __restrict__ rbufb,
                   int N) {
    __shared__ __align__(16) unsigned short alds[64 * LDA];
    int n0 = blockIdx.x * 64;
    int t = threadIdx.x;
    // agg-half: 64 rows x 16 chunks (16B = 8 bf16)
#pragma unroll
    for (int i = 0; i < 4; ++i) {
        int cid = t + i * 256;
        int row = cid >> 4, ca = cid & 15;
        int gr = n0 + row;
        uint4 v = make_uint4(0, 0, 0, 0);
        if (gr < N) v = *(const uint4*)(aggm + (size_t)gr * 128 + ca * 8);
        *(uint4*)&alds[row * LDA + ca * 8] = v;
    }
    // x-half: 64 rows x 16 chunks (8 fp8 -> 8 bf16); e4m3 -> bf16 is exact
#pragma unroll
    for (int i = 0; i < 4; ++i) {
        int cid = t + i * 256;
        int row = cid >> 4, cx = cid & 15;
        int gr = n0 + row;
        uint2 v8 = make_uint2(0u, 0u);
        if (gr < N) v8 = *(const uint2*)(xf8b + (size_t)gr * 128 + cx * 8);
        f32x2 f0 = __builtin_amdgcn_cvt_pk_f32_fp8((int)v8.x, false);
        f32x2 f1 = __builtin_amdgcn_cvt_pk_f32_fp8((int)v8.x, true);
        f32x2 f2 = __builtin_amdgcn_cvt_pk_f32_fp8((int)v8.y, false);
        f32x2 f3 = __builtin_amdgcn_cvt_pk_f32_fp8((int)v8.y, true);
        uint4 ov;
        ov.x = ((unsigned)f2bf(f0.y) << 16) | f2bf(f0.x);
        ov.y = ((unsigned)f2bf(f1.y) << 16) | f2bf(f1.x);
        ov.z = ((unsigned)f2bf(f2.y) << 16) | f2bf(f2.x);
        ov.w = ((unsigned)f2bf(f3.y) << 16) | f2bf(f3.x);
        *(uint4*)&alds[row * LDA + 128 + cx * 8] = ov;
    }
    __syncthreads();
    int wid = t >> 6, lane = t & 63;
    int l15 = lane & 15, g = lane >> 4;
    int col0 = wid * 64;
    f32x4 acc[4][4];
#pragma unroll
    for (int mf = 0; mf < 4; ++mf)
#pragma unroll
        for (int nf = 0; nf < 4; ++nf) acc[mf][nf] = (f32x4)(0.0f);
    for (int ks = 0; ks < 8; ++ks) {
        short8 af[4], bfr[4];
#pragma unroll
        for (int mf = 0; mf < 4; ++mf)
            af[mf] = *(const short8*)&alds[(mf * 16 + l15) * LDA + ks * 32 + g * 8];
#pragma unroll
        for (int nf = 0; nf < 4; ++nf)
            bfr[nf] = *(const short8*)&Bp1[((size_t)ks * 256 + col0 + nf * 16 + l15) * 32 + g * 8];
#pragma unroll
        for (int mf = 0; mf < 4; ++mf)
#pragma unroll
            for (int nf = 0; nf < 4; ++nf)
                acc[mf][nf] = __builtin_amdgcn_mfma_f32_16x16x32_bf16(
                    af[mf], bfr[nf], acc[mf][nf], 0, 0, 0);
    }
    float bc[4];
#pragma unroll
    for (int nf = 0; nf < 4; ++nf) bc[nf] = b1[col0 + nf * 16 + l15];
    __syncthreads();   // all alds reads done; reuse alds for h1 tile
#pragma unroll
    for (int mf = 0; mf < 4; ++mf) {
#pragma unroll
        for (int r = 0; r < 4; ++r) {
            int row = mf * 16 + g * 4 + r;
#pragma unroll
            for (int nf = 0; nf < 4; ++nf)
                alds[row * LDA + col0 + nf * 16 + l15] =
                    f2bf(fmaxf(acc[mf][nf][r] + bc[nf], 0.0f));
        }
    }
    __syncthreads();
    // ---- phase 2: zb8/rbufb from LDS h1 tile ----
    int wr = wid >> 1, wc = wid & 1;
    f32x4 acc2[2][3];
#pragma unroll
    for (int mf = 0; mf < 2; ++mf)
#pragma unroll
        for (int nf = 0; nf < 3; ++nf) acc2[mf][nf] = (f32x4)(0.0f);
    for (int ks = 0; ks < 8; ++ks) {
        short8 af[2], bfr[3];
#pragma unroll
        for (int mf = 0; mf < 2; ++mf)
            af[mf] = *(const short8*)&alds[(wr * 32 + mf * 16 + l15) * LDA + ks * 32 + g * 8];
#pragma unroll
        for (int nf = 0; nf < 3; ++nf)
            bfr[nf] = *(const short8*)&Bp2[((size_t)ks * 96 + wc * 48 + nf * 16 + l15) * 32 + g * 8];
#pragma unroll
        for (int mf = 0; mf < 2; ++mf)
#pragma unroll
            for (int nf = 0; nf < 3; ++nf)
                acc2[mf][nf] = __builtin_amdgcn_mfma_f32_16x16x32_bf16(
                    af[mf], bfr[nf], acc2[mf][nf], 0, 0, 0);
    }
#pragma unroll
    for (int nf = 0; nf < 3; ++nf) {
        int col = wc * 48 + nf * 16 + l15;
        float bb = (col >= 48 && col < 89) ? b2[col - 48] : 0.0f;
#pragma unroll
        for (int mf = 0; mf < 2; ++mf) {
            int rowb = n0 + wr * 32 + mf * 16 + g * 4;
#pragma unroll
            for (int r = 0; r < 4; ++r) {
                int row = rowb + r;
                if (row < N) {
                    float v = acc2[mf][nf][r];
                    if (col < 41) {
                        unsigned u = __builtin_amdgcn_cvt_pk_fp8_f32(v, 0.0f, 0, false);
                        zb8[(size_t)row * CPAD + col] = (unsigned char)(u & 0xff);
                    } else if (col >= 48 && col < 89) {
                        rbufb[(size_t)row * CPAD + (col - 48)] = f2bf(v + bb);
                    }
                }
            }
        }
    }
}

// -- gather2+final: 4 nodes/wave (16 lanes each, uint = 4 fp8), unroll-4 -----
__global__ void __launch_bounds__(256)
gather2_kernel(const unsigned* __restrict__ zp8, const unsigned short* __restrict__ rbufb,
               const int* __restrict__ row_start,
               const int* __restrict__ csr_src, float* __restrict__ out, int N) {
    int tid = blockIdx.x * 256 + threadIdx.x;
    int nid = tid >> 4;
    int l = tid & 15;
    if (nid >= N) return;
    int rs = row_start[nid];
    int d = row_start[nid + 1] - rs;
    float a[4][4];
#pragma unroll
    for (int j = 0; j < 4; ++j)
#pragma unroll
        for (int k = 0; k < 4; ++k) a[j][k] = 0.f;
    int i = 0;
    for (; i + 4 <= d; i += 4) {
        int s[4];
#pragma unroll
        for (int j = 0; j < 4; ++j) s[j] = csr_src[rs + i + j];
        unsigned u[4];
#pragma unroll
        for (int j = 0; j < 4; ++j) u[j] = zp8[(size_t)s[j] * 16 + l];
#pragma unroll
        for (int j = 0; j < 4; ++j) {
            f32x2 lo = __builtin_amdgcn_cvt_pk_f32_fp8((int)u[j], false);
            f32x2 hi = __builtin_amdgcn_cvt_pk_f32_fp8((int)u[j], true);
            a[j][0] += lo.x; a[j][1] += lo.y; a[j][2] += hi.x; a[j][3] += hi.y;
        }
    }
    for (; i < d; ++i) {
        unsigned u0 = zp8[(size_t)csr_src[rs + i] * 16 + l];
        f32x2 lo = __builtin_amdgcn_cvt_pk_f32_fp8((int)u0, false);
        f32x2 hi = __builtin_amdgcn_cvt_pk_f32_fp8((int)u0, true);
        a[0][0] += lo.x; a[0][1] += lo.y; a[0][2] += hi.x; a[0][3] += hi.y;
    }
    float inv = 1.0f / fmaxf((float)d, 1.0f);
    ushort4 rb4 = *(const ushort4*)&rbufb[(size_t)nid * CPAD + 4 * l];
    float rbv[4] = {bf2f(rb4.x), bf2f(rb4.y), bf2f(rb4.z), bf2f(rb4.w)};
    float v[4];
#pragma unroll
    for (int k = 0; k < 4; ++k) {
        int col = 4 * l + k;
        v[k] = (col < CLASSES)
             ? ((a[0][k] + a[1][k]) + (a[2][k] + a[3][k])) * inv + rbv[k]
             : -INFINITY;
    }
    float m = fmaxf(fmaxf(v[0], v[1]), fmaxf(v[2], v[3]));
#pragma unroll
    for (int off = 8; off; off >>= 1) m = fmaxf(m, __shfl_xor(m, off, 16));
    float s = 0.f;
#pragma unroll
    for (int k = 0; k < 4; ++k)
        s += (4 * l + k < CLASSES) ? expf(v[k] - m) : 0.0f;
#pragma unroll
    for (int off = 8; off; off >>= 1) s += __shfl_xor(s, off, 16);
    float lse = m + logf(s);
#pragma unroll
    for (int k = 0; k < 4; ++k) {
        int col = 4 * l + k;
        if (col < CLASSES) out[(size_t)nid * CLASSES + col] = v[k] - lse;
    }
}

extern "C" void kernel_launch(void* const* d_in, const int* in_sizes, int n_in,
                              void* d_out, int out_size, void* d_ws, size_t ws_size,
                              hipStream_t stream) {
    const float* x   = (const float*)d_in[0];
    const int*   ei  = (const int*)d_in[1];
    const float* W1l = (const float*)d_in[2];
    const float* W1r = (const float*)d_in[3];
    const float* b1  = (const float*)d_in[4];
    const float* W2l = (const float*)d_in[5];
    const float* W2r = (const float*)d_in[6];
    const float* b2  = (const float*)d_in[7];
    float* out = (float*)d_out;

    int N = in_sizes[0] / IN_FEATS;
    int E = in_sizes[1] / 2;
    const int* src = ei;
    const int* dst = ei + E;

    int NB   = (N + 127) >> BSH;
    int NBLK = (E + CHUNK - 1) / CHUNK;
    int L    = NB * NBLK;

    // ints: [mat L+1][blk_sums 256][row_start N+1][tmp E (u32)][csr_src E]
    int* ws_i      = (int*)d_ws;
    int* mat       = ws_i;
    int* blk_sums  = ws_i + (size_t)L + 1;
    int* row_start = blk_sums + 256;
    unsigned* tmp  = (unsigned*)(row_start + (size_t)N + 1);
    int* csr_src   = (int*)(tmp + (size_t)E);
    size_t int_bytes = ((size_t)L + 1 + 256 + (size_t)N + 1 + 2 * (size_t)E) * sizeof(int);
    char* p = (char*)d_ws + ((int_bytes + 15) & ~(size_t)15);
    unsigned*       xf8   = (unsigned*)p;                 p += (size_t)N * 128;
    unsigned short* aggm  = (unsigned short*)p;           p += (size_t)N * 128 * 2;
    unsigned short* Bp1   = (unsigned short*)p;           p += 65536 * 2;
    unsigned short* Bp2   = (unsigned short*)p;           p += 24576 * 2;
    unsigned char*  zb8   = (unsigned char*)p;            p += (size_t)N * CPAD;
    unsigned short* rbufb = (unsigned short*)p;

    // ---- CSR construction (no global atomics) ----
    passA_kernel<<<NBLK, 256, 0, stream>>>(dst, mat, E, NB, NBLK);
    int nscanM = (L + 1 + SCAN_BLK - 1) / SCAN_BLK;
    scanM1_kernel<<<nscanM, 256, 0, stream>>>(mat, blk_sums, L);
    scan2_kernel<<<1, 256, 0, stream>>>(blk_sums, nscanM);
    scanM3_kernel<<<(L + 1 + 255) / 256, 256, 0, stream>>>(mat, blk_sums, L);
    passB_kernel<<<NBLK, 256, 0, stream>>>(src, dst, mat, tmp, E, NB, NBLK);
    passC_kernel<<<NB, 256, 0, stream>>>(tmp, mat, row_start, csr_src, E, N, NB, NBLK);

    // ---- x->fp8 + weight pack (one launch; xf8 warm for gather1) ----
    long n4 = (long)N * 128 / 4;
    int XB = (int)((n4 + 255) / 256);
    int PB = (65536 + 24576) / 256;
    cvtprep_kernel<<<XB + PB, 256, 0, stream>>>(x, xf8, n4, XB,
                                                W1l, W1r, W2l, W2r, Bp1, Bp2);

    {
        long long threads = (long long)N * 64;
        gather1_kernel<<<(int)((threads + 255) / 256), 256, 0, stream>>>(
            (const unsigned short*)xf8, row_start, csr_src, aggm, N);
    }
    int gblocks = (N + 63) / 64;
    mgemm_fused_kernel<<<gblocks, 256, 0, stream>>>(aggm, (const unsigned char*)xf8,
                                                    Bp1, b1, Bp2, b2, zb8, rbufb, N);
    {
        long long threads = (long long)N * 16;
        gather2_kernel<<<(int)((threads + 255) / 256), 256, 0, stream>>>(
            (const unsigned*)zb8, rbufb, row_start, csr_src, out, N);
    }
}

// Round 15
// 201.756 us; speedup vs baseline: 1.9357x; 1.0178x over previous
//
#include <hip/hip_runtime.h>
#include <math.h>

#define IN_FEATS 128
#define HIDDEN   256
#define CLASSES  41
#define CPAD     64
#define SCAN_BLK 1024
#define LDA      264    // 256 + 8 pad (bf16 elems)
#define CHUNK    4096   // edges per block in passA/passB
#define BSH      7      // bucket = dst >> 7 (128 nodes per bucket)
#define NBMAX    1024   // max buckets (N <= 131072)

typedef __attribute__((ext_vector_type(8))) short short8;
typedef __attribute__((ext_vector_type(4))) float f32x4;
typedef __attribute__((ext_vector_type(2))) float f32x2;

__device__ __forceinline__ unsigned short f2bf(float f) {
    union { float f; unsigned u; } v; v.f = f;
    unsigned r = v.u + 0x7FFF + ((v.u >> 16) & 1);
    return (unsigned short)(r >> 16);
}
__device__ __forceinline__ float bf2f(unsigned short h) {
    union { unsigned u; float f; } v; v.u = ((unsigned)h) << 16;
    return v.f;
}

// ---- passA: per-chunk LDS histogram over buckets -> mat[b*NBLK + blk] ------
__global__ void __launch_bounds__(256)
passA_kernel(const int* __restrict__ dst, int* __restrict__ mat,
             int E, int NB, int NBLK) {
    __shared__ int hist[NBMAX];
    int blk = blockIdx.x, t = threadIdx.x;
    for (int b = t; b < NB; b += 256) hist[b] = 0;
    __syncthreads();
    int e0 = blk * CHUNK;
    for (int i = t; i < CHUNK; i += 256) {
        int e = e0 + i;
        if (e < E) atomicAdd(&hist[dst[e] >> BSH], 1);
    }
    __syncthreads();
    for (int b = t; b < NB; b += 256) mat[b * NBLK + blk] = hist[b];
}

// ---- 3-phase exclusive scan of mat[0..L] (sentinel at L) -------------------
__global__ void __launch_bounds__(256)
scanM1_kernel(int* __restrict__ a, int* __restrict__ bs, int L) {
    __shared__ int lds[256];
    int base = blockIdx.x * SCAN_BLK;
    int t = threadIdx.x;
    int v[4];
    int s = 0;
#pragma unroll
    for (int i = 0; i < 4; ++i) {
        int idx = base + t * 4 + i;
        v[i] = (idx < L) ? a[idx] : 0;
        s += v[i];
    }
    lds[t] = s;
    __syncthreads();
    for (int off = 1; off < 256; off <<= 1) {
        int val = lds[t];
        int add = (t >= off) ? lds[t - off] : 0;
        __syncthreads();
        lds[t] = val + add;
        __syncthreads();
    }
    if (t == 255) bs[blockIdx.x] = lds[255];
    int run = (t == 0) ? 0 : lds[t - 1];
#pragma unroll
    for (int i = 0; i < 4; ++i) {
        int idx = base + t * 4 + i;
        if (idx <= L) a[idx] = run;
        run += v[i];
    }
}

__global__ void __launch_bounds__(512)
scan2_kernel(int* __restrict__ bs, int nb) {
    __shared__ int lds[512];
    int t = threadIdx.x;
    lds[t] = (t < nb) ? bs[t] : 0;
    __syncthreads();
    for (int off = 1; off < 512; off <<= 1) {
        int val = lds[t];
        int add = (t >= off) ? lds[t - off] : 0;
        __syncthreads();
        lds[t] = val + add;
        __syncthreads();
    }
    if (t < nb) bs[t] = (t == 0) ? 0 : lds[t - 1];
}

__global__ void __launch_bounds__(256)
scanM3_kernel(int* __restrict__ a, const int* __restrict__ bs, int L) {
    int idx = blockIdx.x * 256 + threadIdx.x;
    if (idx <= L) a[idx] += bs[idx / SCAN_BLK];
}

// ---- passB: scatter packed (src<<7 | dst&127) to bucket-major tmp ----------
__global__ void __launch_bounds__(256)
passB_kernel(const int* __restrict__ src, const int* __restrict__ dst,
             const int* __restrict__ mat, unsigned* __restrict__ tmp,
             int E, int NB, int NBLK) {
    __shared__ int cursor[NBMAX];
    int blk = blockIdx.x, t = threadIdx.x;
    for (int b = t; b < NB; b += 256) cursor[b] = mat[b * NBLK + blk];
    __syncthreads();
    int e0 = blk * CHUNK;
    for (int i = t; i < CHUNK; i += 256) {
        int e = e0 + i;
        if (e < E) {
            int d = dst[e], s = src[e];
            int b = d >> BSH;
            int pos = atomicAdd(&cursor[b], 1);
            tmp[pos] = (unsigned)((s << BSH) | (d & 127));
        }
    }
}

// ---- passC: per-bucket fine CSR: row_start + csr_src -----------------------
__global__ void __launch_bounds__(256)
passC_kernel(const unsigned* __restrict__ tmp, const int* __restrict__ mat,
             int* __restrict__ row_start, int* __restrict__ csr_src,
             int E, int N, int NB, int NBLK) {
    __shared__ int h[128], cur[128], sc[128];
    int b = blockIdx.x, t = threadIdx.x;
    int segBase = mat[b * NBLK];
    int segEnd  = mat[(b + 1) * NBLK];
    int len = segEnd - segBase;
    if (t < 128) h[t] = 0;
    __syncthreads();
    for (int i = t; i < len; i += 256)
        atomicAdd(&h[tmp[segBase + i] & 127], 1);
    __syncthreads();
    if (t < 128) sc[t] = h[t];
    __syncthreads();
    for (int off = 1; off < 128; off <<= 1) {
        int v2 = 0;
        if (t < 128) { v2 = sc[t]; if (t >= off) v2 += sc[t - off]; }
        __syncthreads();
        if (t < 128) sc[t] = v2;
        __syncthreads();
    }
    if (t < 128) {
        int base = segBase + sc[t] - h[t];
        cur[t] = base;
        int n = (b << BSH) + t;
        if (n < N) row_start[n] = base;
    }
    if (b == NB - 1 && t == 0) row_start[N] = segEnd;
    __syncthreads();
    for (int i = t; i < len; i += 256) {
        unsigned w = tmp[segBase + i];
        int pos = atomicAdd(&cur[w & 127], 1);
        csr_src[pos] = (int)(w >> BSH);
    }
}

// ---- cvtprep: x -> fp8 (blocks [0,XB)) ; weight pack (rest) ----------------
__global__ void __launch_bounds__(256)
cvtprep_kernel(const float* __restrict__ x, unsigned* __restrict__ xf8,
               long n4, int XB,
               const float* __restrict__ W1l, const float* __restrict__ W1r,
               const float* __restrict__ W2l, const float* __restrict__ W2r,
               unsigned short* __restrict__ Bp1, unsigned short* __restrict__ Bp2) {
    int b = blockIdx.x, t = threadIdx.x;
    if (b < XB) {
        long i = (long)b * 256 + t;
        if (i < n4) {
            float4 v = *(const float4*)(x + i * 4);
            unsigned u = __builtin_amdgcn_cvt_pk_fp8_f32(v.x, v.y, 0, false);
            u = __builtin_amdgcn_cvt_pk_fp8_f32(v.z, v.w, u, true);
            xf8[i] = u;
        }
        return;
    }
    int idx = (b - XB) * 256 + t;
    if (idx < 256 * 256) {
        int k = idx >> 8, c = idx & 255;
        float v = (k < 128) ? W1l[k * 256 + c] : W1r[(k - 128) * 256 + c];
        Bp1[((k >> 5) * 256 + c) * 32 + ((k & 31) >> 3) * 8 + (k & 7)] = f2bf(v);
    } else {
        int j = idx - 65536;
        if (j < 256 * 96) {
            int k = j / 96, c = j % 96;
            float v = 0.0f;
            if (c < 41) v = W2l[k * 41 + c];
            else if (c >= 48 && c < 89) v = W2r[k * 41 + (c - 48)];
            Bp2[((k >> 5) * 96 + c) * 32 + ((k & 31) >> 3) * 8 + (k & 7)] = f2bf(v);
        }
    }
}

// ------- gather1: aggm_bf[n] = bf16(mean_{s} xf8[s]), unroll-8, pk-add ------
__global__ void __launch_bounds__(256)
gather1_kernel(const unsigned short* __restrict__ xf8,
               const int* __restrict__ row_start,
               const int* __restrict__ csr_src, unsigned short* __restrict__ aggm,
               int N) {
    int wid = (blockIdx.x * 256 + threadIdx.x) >> 6;
    int lane = threadIdx.x & 63;
    if (wid >= N) return;
    int rs = row_start[wid];
    int d = row_start[wid + 1] - rs;
    f32x2 acc[8];
#pragma unroll
    for (int j = 0; j < 8; ++j) acc[j] = (f32x2)(0.0f);
    int i = 0;
    for (; i + 8 <= d; i += 8) {
        int s[8];
#pragma unroll
        for (int j = 0; j < 8; ++j) s[j] = csr_src[rs + i + j];
        unsigned short u[8];
#pragma unroll
        for (int j = 0; j < 8; ++j) u[j] = xf8[(size_t)s[j] * 64 + lane];
#pragma unroll
        for (int j = 0; j < 8; ++j)
            acc[j] += __builtin_amdgcn_cvt_pk_f32_fp8((int)u[j], false);
    }
    for (; i + 4 <= d; i += 4) {
        int s[4];
#pragma unroll
        for (int j = 0; j < 4; ++j) s[j] = csr_src[rs + i + j];
        unsigned short u[4];
#pragma unroll
        for (int j = 0; j < 4; ++j) u[j] = xf8[(size_t)s[j] * 64 + lane];
#pragma unroll
        for (int j = 0; j < 4; ++j)
            acc[j] += __builtin_amdgcn_cvt_pk_f32_fp8((int)u[j], false);
    }
    for (; i < d; ++i) {
        unsigned short u0 = xf8[(size_t)csr_src[rs + i] * 64 + lane];
        acc[0] += __builtin_amdgcn_cvt_pk_f32_fp8((int)u0, false);
    }
    f32x2 tot = ((acc[0] + acc[1]) + (acc[2] + acc[3]))
              + ((acc[4] + acc[5]) + (acc[6] + acc[7]));
    float inv = 1.0f / fmaxf((float)d, 1.0f);
    unsigned o = ((unsigned)f2bf(tot.y * inv) << 16) | (unsigned)f2bf(tot.x * inv);
    ((unsigned*)aggm)[(size_t)wid * 64 + lane] = o;
}

// ---- fused mgemm: stage [aggm bf16 | xf8->bf16] in LDS; h1 = relu(A@Bp1+b1)
//      kept in LDS; then zb8 = fp8(h1@W2l), rbufb = bf16(h1@W2r + b2) --------
__global__ void __launch_bounds__(256)
mgemm_fused_kernel(const unsigned short* __restrict__ aggm,
                   const unsigned char* __restrict__ xf8b,
                   const unsigned short* __restrict__ Bp1, const float* __restrict__ b1,
                   const unsigned short* __restrict__ Bp2, const float* __restrict__ b2,
                   unsigned char* __restrict__ zb8, unsigned short* __restrict__ rbufb,
                   int N) {
    __shared__ __align__(16) unsigned short alds[64 * LDA];
    int n0 = blockIdx.x * 64;
    int t = threadIdx.x;
#pragma unroll
    for (int i = 0; i < 4; ++i) {
        int cid = t + i * 256;
        int row = cid >> 4, ca = cid & 15;
        int gr = n0 + row;
        uint4 v = make_uint4(0, 0, 0, 0);
        if (gr < N) v = *(const uint4*)(aggm + (size_t)gr * 128 + ca * 8);
        *(uint4*)&alds[row * LDA + ca * 8] = v;
    }
#pragma unroll
    for (int i = 0; i < 4; ++i) {
        int cid = t + i * 256;
        int row = cid >> 4, cx = cid & 15;
        int gr = n0 + row;
        uint2 v8 = make_uint2(0u, 0u);
        if (gr < N) v8 = *(const uint2*)(xf8b + (size_t)gr * 128 + cx * 8);
        f32x2 f0 = __builtin_amdgcn_cvt_pk_f32_fp8((int)v8.x, false);
        f32x2 f1 = __builtin_amdgcn_cvt_pk_f32_fp8((int)v8.x, true);
        f32x2 f2 = __builtin_amdgcn_cvt_pk_f32_fp8((int)v8.y, false);
        f32x2 f3 = __builtin_amdgcn_cvt_pk_f32_fp8((int)v8.y, true);
        uint4 ov;
        ov.x = ((unsigned)f2bf(f0.y) << 16) | f2bf(f0.x);
        ov.y = ((unsigned)f2bf(f1.y) << 16) | f2bf(f1.x);
        ov.z = ((unsigned)f2bf(f2.y) << 16) | f2bf(f2.x);
        ov.w = ((unsigned)f2bf(f3.y) << 16) | f2bf(f3.x);
        *(uint4*)&alds[row * LDA + 128 + cx * 8] = ov;
    }
    __syncthreads();
    int wid = t >> 6, lane = t & 63;
    int l15 = lane & 15, g = lane >> 4;
    int col0 = wid * 64;
    f32x4 acc[4][4];
#pragma unroll
    for (int mf = 0; mf < 4; ++mf)
#pragma unroll
        for (int nf = 0; nf < 4; ++nf) acc[mf][nf] = (f32x4)(0.0f);
    for (int ks = 0; ks < 8; ++ks) {
        short8 af[4], bfr[4];
#pragma unroll
        for (int mf = 0; mf < 4; ++mf)
            af[mf] = *(const short8*)&alds[(mf * 16 + l15) * LDA + ks * 32 + g * 8];
#pragma unroll
        for (int nf = 0; nf < 4; ++nf)
            bfr[nf] = *(const short8*)&Bp1[((size_t)ks * 256 + col0 + nf * 16 + l15) * 32 + g * 8];
#pragma unroll
        for (int mf = 0; mf < 4; ++mf)
#pragma unroll
            for (int nf = 0; nf < 4; ++nf)
                acc[mf][nf] = __builtin_amdgcn_mfma_f32_16x16x32_bf16(
                    af[mf], bfr[nf], acc[mf][nf], 0, 0, 0);
    }
    float bc[4];
#pragma unroll
    for (int nf = 0; nf < 4; ++nf) bc[nf] = b1[col0 + nf * 16 + l15];
    __syncthreads();
#pragma unroll
    for (int mf = 0; mf < 4; ++mf) {
#pragma unroll
        for (int r = 0; r < 4; ++r) {
            int row = mf * 16 + g * 4 + r;
#pragma unroll
            for (int nf = 0; nf < 4; ++nf)
                alds[row * LDA + col0 + nf * 16 + l15] =
                    f2bf(fmaxf(acc[mf][nf][r] + bc[nf], 0.0f));
        }
    }
    __syncthreads();
    int wr = wid >> 1, wc = wid & 1;
    f32x4 acc2[2][3];
#pragma unroll
    for (int mf = 0; mf < 2; ++mf)
#pragma unroll
        for (int nf = 0; nf < 3; ++nf) acc2[mf][nf] = (f32x4)(0.0f);
    for (int ks = 0; ks < 8; ++ks) {
        short8 af[2], bfr[3];
#pragma unroll
        for (int mf = 0; mf < 2; ++mf)
            af[mf] = *(const short8*)&alds[(wr * 32 + mf * 16 + l15) * LDA + ks * 32 + g * 8];
#pragma unroll
        for (int nf = 0; nf < 3; ++nf)
            bfr[nf] = *(const short8*)&Bp2[((size_t)ks * 96 + wc * 48 + nf * 16 + l15) * 32 + g * 8];
#pragma unroll
        for (int mf = 0; mf < 2; ++mf)
#pragma unroll
            for (int nf = 0; nf < 3; ++nf)
                acc2[mf][nf] = __builtin_amdgcn_mfma_f32_16x16x32_bf16(
                    af[mf], bfr[nf], acc2[mf][nf], 0, 0, 0);
    }
#pragma unroll
    for (int nf = 0; nf < 3; ++nf) {
        int col = wc * 48 + nf * 16 + l15;
        float bb = (col >= 48 && col < 89) ? b2[col - 48] : 0.0f;
#pragma unroll
        for (int mf = 0; mf < 2; ++mf) {
            int rowb = n0 + wr * 32 + mf * 16 + g * 4;
#pragma unroll
            for (int r = 0; r < 4; ++r) {
                int row = rowb + r;
                if (row < N) {
                    float v = acc2[mf][nf][r];
                    if (col < 41) {
                        unsigned u = __builtin_amdgcn_cvt_pk_fp8_f32(v, 0.0f, 0, false);
                        zb8[(size_t)row * CPAD + col] = (unsigned char)(u & 0xff);
                    } else if (col >= 48 && col < 89) {
                        rbufb[(size_t)row * CPAD + (col - 48)] = f2bf(v + bb);
                    }
                }
            }
        }
    }
}

// -- gather2+final: 4 nodes/wave (16 lanes each, uint = 4 fp8), pk-add -------
__global__ void __launch_bounds__(256)
gather2_kernel(const unsigned* __restrict__ zp8, const unsigned short* __restrict__ rbufb,
               const int* __restrict__ row_start,
               const int* __restrict__ csr_src, float* __restrict__ out, int N) {
    int tid = blockIdx.x * 256 + threadIdx.x;
    int nid = tid >> 4;
    int l = tid & 15;
    if (nid >= N) return;
    int rs = row_start[nid];
    int d = row_start[nid + 1] - rs;
    f32x2 a2[4][2];
#pragma unroll
    for (int j = 0; j < 4; ++j) { a2[j][0] = (f32x2)(0.0f); a2[j][1] = (f32x2)(0.0f); }
    int i = 0;
    for (; i + 4 <= d; i += 4) {
        int s[4];
#pragma unroll
        for (int j = 0; j < 4; ++j) s[j] = csr_src[rs + i + j];
        unsigned u[4];
#pragma unroll
        for (int j = 0; j < 4; ++j) u[j] = zp8[(size_t)s[j] * 16 + l];
#pragma unroll
        for (int j = 0; j < 4; ++j) {
            a2[j][0] += __builtin_amdgcn_cvt_pk_f32_fp8((int)u[j], false);
            a2[j][1] += __builtin_amdgcn_cvt_pk_f32_fp8((int)u[j], true);
        }
    }
    for (; i < d; ++i) {
        unsigned u0 = zp8[(size_t)csr_src[rs + i] * 16 + l];
        a2[0][0] += __builtin_amdgcn_cvt_pk_f32_fp8((int)u0, false);
        a2[0][1] += __builtin_amdgcn_cvt_pk_f32_fp8((int)u0, true);
    }
    f32x2 lo = (a2[0][0] + a2[1][0]) + (a2[2][0] + a2[3][0]);
    f32x2 hi = (a2[0][1] + a2[1][1]) + (a2[2][1] + a2[3][1]);
    float inv = 1.0f / fmaxf((float)d, 1.0f);
    ushort4 rb4 = *(const ushort4*)&rbufb[(size_t)nid * CPAD + 4 * l];
    float av[4] = {lo.x, lo.y, hi.x, hi.y};
    float rbv[4] = {bf2f(rb4.x), bf2f(rb4.y), bf2f(rb4.z), bf2f(rb4.w)};
    float v[4];
#pragma unroll
    for (int k = 0; k < 4; ++k) {
        int col = 4 * l + k;
        v[k] = (col < CLASSES) ? av[k] * inv + rbv[k] : -INFINITY;
    }
    float m = fmaxf(fmaxf(v[0], v[1]), fmaxf(v[2], v[3]));
#pragma unroll
    for (int off = 8; off; off >>= 1) m = fmaxf(m, __shfl_xor(m, off, 16));
    float s = 0.f;
#pragma unroll
    for (int k = 0; k < 4; ++k)
        s += (4 * l + k < CLASSES) ? expf(v[k] - m) : 0.0f;
#pragma unroll
    for (int off = 8; off; off >>= 1) s += __shfl_xor(s, off, 16);
    float lse = m + logf(s);
#pragma unroll
    for (int k = 0; k < 4; ++k) {
        int col = 4 * l + k;
        if (col < CLASSES) out[(size_t)nid * CLASSES + col] = v[k] - lse;
    }
}

extern "C" void kernel_launch(void* const* d_in, const int* in_sizes, int n_in,
                              void* d_out, int out_size, void* d_ws, size_t ws_size,
                              hipStream_t stream) {
    const float* x   = (const float*)d_in[0];
    const int*   ei  = (const int*)d_in[1];
    const float* W1l = (const float*)d_in[2];
    const float* W1r = (const float*)d_in[3];
    const float* b1  = (const float*)d_in[4];
    const float* W2l = (const float*)d_in[5];
    const float* W2r = (const float*)d_in[6];
    const float* b2  = (const float*)d_in[7];
    float* out = (float*)d_out;

    int N = in_sizes[0] / IN_FEATS;
    int E = in_sizes[1] / 2;
    const int* src = ei;
    const int* dst = ei + E;

    int NB   = (N + 127) >> BSH;
    int NBLK = (E + CHUNK - 1) / CHUNK;
    int L    = NB * NBLK;

    // ints: [mat L+1][blk_sums 512][row_start N+1][tmp E (u32)][csr_src E]
    int* ws_i      = (int*)d_ws;
    int* mat       = ws_i;
    int* blk_sums  = ws_i + (size_t)L + 1;
    int* row_start = blk_sums + 512;
    unsigned* tmp  = (unsigned*)(row_start + (size_t)N + 1);
    int* csr_src   = (int*)(tmp + (size_t)E);
    size_t int_bytes = ((size_t)L + 1 + 512 + (size_t)N + 1 + 2 * (size_t)E) * sizeof(int);
    char* p = (char*)d_ws + ((int_bytes + 15) & ~(size_t)15);
    unsigned*       xf8   = (unsigned*)p;                 p += (size_t)N * 128;
    unsigned short* aggm  = (unsigned short*)p;           p += (size_t)N * 128 * 2;
    unsigned short* Bp1   = (unsigned short*)p;           p += 65536 * 2;
    unsigned short* Bp2   = (unsigned short*)p;           p += 24576 * 2;
    unsigned char*  zb8   = (unsigned char*)p;            p += (size_t)N * CPAD;
    unsigned short* rbufb = (unsigned short*)p;

    // ---- CSR construction (no global atomics) ----
    passA_kernel<<<NBLK, 256, 0, stream>>>(dst, mat, E, NB, NBLK);
    int nscanM = (L + 1 + SCAN_BLK - 1) / SCAN_BLK;   // <= 512
    scanM1_kernel<<<nscanM, 256, 0, stream>>>(mat, blk_sums, L);
    scan2_kernel<<<1, 512, 0, stream>>>(blk_sums, nscanM);
    scanM3_kernel<<<(L + 1 + 255) / 256, 256, 0, stream>>>(mat, blk_sums, L);
    passB_kernel<<<NBLK, 256, 0, stream>>>(src, dst, mat, tmp, E, NB, NBLK);
    passC_kernel<<<NB, 256, 0, stream>>>(tmp, mat, row_start, csr_src, E, N, NB, NBLK);

    // ---- x->fp8 + weight pack (one launch; xf8 warm for gather1) ----
    long n4 = (long)N * 128 / 4;
    int XB = (int)((n4 + 255) / 256);
    int PB = (65536 + 24576) / 256;
    cvtprep_kernel<<<XB + PB, 256, 0, stream>>>(x, xf8, n4, XB,
                                                W1l, W1r, W2l, W2r, Bp1, Bp2);

    {
        long long threads = (long long)N * 64;
        gather1_kernel<<<(int)((threads + 255) / 256), 256, 0, stream>>>(
            (const unsigned short*)xf8, row_start, csr_src, aggm, N);
    }
    int gblocks = (N + 63) / 64;
    mgemm_fused_kernel<<<gblocks, 256, 0, stream>>>(aggm, (const unsigned char*)xf8,
                                                    Bp1, b1, Bp2, b2, zb8, rbufb, N);
    {
        long long threads = (long long)N * 16;
        gather2_kernel<<<(int)((threads + 255) / 256), 256, 0, stream>>>(
            (const unsigned*)zb8, rbufb, row_start, csr_src, out, N);
    }
}

// Round 16
// 195.667 us; speedup vs baseline: 1.9960x; 1.0311x over previous
//
#include <hip/hip_runtime.h>
#include <math.h>

#define IN_FEATS 128
#define HIDDEN   256
#define CLASSES  41
#define CPAD     64
#define SCAN_BLK 1024
#define LDA      264    // 256 + 8 pad (bf16 elems)
#define CHUNK    4096   // edges per block in passA/passB
#define BSH      7      // bucket = dst >> 7 (128 nodes per bucket)
#define NBMAX    1024   // max buckets (N <= 131072)

typedef __attribute__((ext_vector_type(8))) short short8;
typedef __attribute__((ext_vector_type(4))) float f32x4;
typedef __attribute__((ext_vector_type(2))) float f32x2;

__device__ __forceinline__ unsigned short f2bf(float f) {
    union { float f; unsigned u; } v; v.f = f;
    unsigned r = v.u + 0x7FFF + ((v.u >> 16) & 1);
    return (unsigned short)(r >> 16);
}
__device__ __forceinline__ float bf2f(unsigned short h) {
    union { unsigned u; float f; } v; v.u = ((unsigned)h) << 16;
    return v.f;
}

// ---- prepass (fused): blocks [0,NBLK) = passA hist; [NBLK,NBLK+XB) = x->fp8;
//      rest = weight pack ----------------------------------------------------
__global__ void __launch_bounds__(256)
prepass_kernel(const int* __restrict__ dst, int* __restrict__ mat,
               int E, int NB, int NBLK,
               const float* __restrict__ x, unsigned* __restrict__ xf8,
               long n4, int XB,
               const float* __restrict__ W1l, const float* __restrict__ W1r,
               const float* __restrict__ W2l, const float* __restrict__ W2r,
               unsigned short* __restrict__ Bp1, unsigned short* __restrict__ Bp2) {
    __shared__ int hist[NBMAX];
    int b = blockIdx.x, t = threadIdx.x;
    if (b < NBLK) {
        for (int k = t; k < NB; k += 256) hist[k] = 0;
        __syncthreads();
        int e0 = b * CHUNK;
        for (int i = t; i < CHUNK; i += 256) {
            int e = e0 + i;
            if (e < E) atomicAdd(&hist[dst[e] >> BSH], 1);
        }
        __syncthreads();
        for (int k = t; k < NB; k += 256) mat[k * NBLK + b] = hist[k];
        return;
    }
    int a = b - NBLK;
    if (a < XB) {
        long i = (long)a * 256 + t;
        if (i < n4) {
            float4 v = *(const float4*)(x + i * 4);
            unsigned u = __builtin_amdgcn_cvt_pk_fp8_f32(v.x, v.y, 0, false);
            u = __builtin_amdgcn_cvt_pk_fp8_f32(v.z, v.w, u, true);
            xf8[i] = u;
        }
        return;
    }
    int idx = (a - XB) * 256 + t;
    if (idx < 256 * 256) {
        int k = idx >> 8, c = idx & 255;
        float v = (k < 128) ? W1l[k * 256 + c] : W1r[(k - 128) * 256 + c];
        Bp1[((k >> 5) * 256 + c) * 32 + ((k & 31) >> 3) * 8 + (k & 7)] = f2bf(v);
    } else {
        int j = idx - 65536;
        if (j < 256 * 96) {
            int k = j / 96, c = j % 96;
            float v = 0.0f;
            if (c < 41) v = W2l[k * 41 + c];
            else if (c >= 48 && c < 89) v = W2r[k * 41 + (c - 48)];
            Bp2[((k >> 5) * 96 + c) * 32 + ((k & 31) >> 3) * 8 + (k & 7)] = f2bf(v);
        }
    }
}

// ---- 3-phase exclusive scan of mat[0..L] (sentinel at L) -------------------
__global__ void __launch_bounds__(256)
scanM1_kernel(int* __restrict__ a, int* __restrict__ bs, int L) {
    __shared__ int lds[256];
    int base = blockIdx.x * SCAN_BLK;
    int t = threadIdx.x;
    int v[4];
    int s = 0;
#pragma unroll
    for (int i = 0; i < 4; ++i) {
        int idx = base + t * 4 + i;
        v[i] = (idx < L) ? a[idx] : 0;
        s += v[i];
    }
    lds[t] = s;
    __syncthreads();
    for (int off = 1; off < 256; off <<= 1) {
        int val = lds[t];
        int add = (t >= off) ? lds[t - off] : 0;
        __syncthreads();
        lds[t] = val + add;
        __syncthreads();
    }
    if (t == 255) bs[blockIdx.x] = lds[255];
    int run = (t == 0) ? 0 : lds[t - 1];
#pragma unroll
    for (int i = 0; i < 4; ++i) {
        int idx = base + t * 4 + i;
        if (idx <= L) a[idx] = run;
        run += v[i];
    }
}

__global__ void __launch_bounds__(512)
scan2_kernel(int* __restrict__ bs, int nb) {
    __shared__ int lds[512];
    int t = threadIdx.x;
    lds[t] = (t < nb) ? bs[t] : 0;
    __syncthreads();
    for (int off = 1; off < 512; off <<= 1) {
        int val = lds[t];
        int add = (t >= off) ? lds[t - off] : 0;
        __syncthreads();
        lds[t] = val + add;
        __syncthreads();
    }
    if (t < nb) bs[t] = (t == 0) ? 0 : lds[t - 1];
}

__global__ void __launch_bounds__(256)
scanM3_kernel(int* __restrict__ a, const int* __restrict__ bs, int L) {
    int idx = blockIdx.x * 256 + threadIdx.x;
    if (idx <= L) a[idx] += bs[idx / SCAN_BLK];
}

// ---- passB: scatter packed (src<<7 | dst&127) to bucket-major tmp ----------
__global__ void __launch_bounds__(256)
passB_kernel(const int* __restrict__ src, const int* __restrict__ dst,
             const int* __restrict__ mat, unsigned* __restrict__ tmp,
             int E, int NB, int NBLK) {
    __shared__ int cursor[NBMAX];
    int blk = blockIdx.x, t = threadIdx.x;
    for (int b = t; b < NB; b += 256) cursor[b] = mat[b * NBLK + blk];
    __syncthreads();
    int e0 = blk * CHUNK;
    for (int i = t; i < CHUNK; i += 256) {
        int e = e0 + i;
        if (e < E) {
            int d = dst[e], s = src[e];
            int b = d >> BSH;
            int pos = atomicAdd(&cursor[b], 1);
            tmp[pos] = (unsigned)((s << BSH) | (d & 127));
        }
    }
}

// ---- passC: per-bucket fine CSR: row_start + csr_src -----------------------
__global__ void __launch_bounds__(256)
passC_kernel(const unsigned* __restrict__ tmp, const int* __restrict__ mat,
             int* __restrict__ row_start, int* __restrict__ csr_src,
             int E, int N, int NB, int NBLK) {
    __shared__ int h[128], cur[128], sc[128];
    int b = blockIdx.x, t = threadIdx.x;
    int segBase = mat[b * NBLK];
    int segEnd  = mat[(b + 1) * NBLK];
    int len = segEnd - segBase;
    if (t < 128) h[t] = 0;
    __syncthreads();
    for (int i = t; i < len; i += 256)
        atomicAdd(&h[tmp[segBase + i] & 127], 1);
    __syncthreads();
    if (t < 128) sc[t] = h[t];
    __syncthreads();
    for (int off = 1; off < 128; off <<= 1) {
        int v2 = 0;
        if (t < 128) { v2 = sc[t]; if (t >= off) v2 += sc[t - off]; }
        __syncthreads();
        if (t < 128) sc[t] = v2;
        __syncthreads();
    }
    if (t < 128) {
        int base = segBase + sc[t] - h[t];
        cur[t] = base;
        int n = (b << BSH) + t;
        if (n < N) row_start[n] = base;
    }
    if (b == NB - 1 && t == 0) row_start[N] = segEnd;
    __syncthreads();
    for (int i = t; i < len; i += 256) {
        unsigned w = tmp[segBase + i];
        int pos = atomicAdd(&cur[w & 127], 1);
        csr_src[pos] = (int)(w >> BSH);
    }
}

// ------- gather1: aggm_bf[n] = bf16(mean_{s} xf8[s]), unroll-16/8/4 ---------
__global__ void __launch_bounds__(256)
gather1_kernel(const unsigned short* __restrict__ xf8,
               const int* __restrict__ row_start,
               const int* __restrict__ csr_src, unsigned short* __restrict__ aggm,
               int N) {
    int wid = (blockIdx.x * 256 + threadIdx.x) >> 6;
    int lane = threadIdx.x & 63;
    if (wid >= N) return;
    int rs = row_start[wid];
    int d = row_start[wid + 1] - rs;
    f32x2 acc[8];
#pragma unroll
    for (int j = 0; j < 8; ++j) acc[j] = (f32x2)(0.0f);
    int i = 0;
    for (; i + 16 <= d; i += 16) {
        int s[16];
#pragma unroll
        for (int j = 0; j < 16; ++j) s[j] = csr_src[rs + i + j];
        unsigned short u[16];
#pragma unroll
        for (int j = 0; j < 16; ++j) u[j] = xf8[(size_t)s[j] * 64 + lane];
#pragma unroll
        for (int j = 0; j < 16; ++j)
            acc[j & 7] += __builtin_amdgcn_cvt_pk_f32_fp8((int)u[j], false);
    }
    for (; i + 8 <= d; i += 8) {
        int s[8];
#pragma unroll
        for (int j = 0; j < 8; ++j) s[j] = csr_src[rs + i + j];
        unsigned short u[8];
#pragma unroll
        for (int j = 0; j < 8; ++j) u[j] = xf8[(size_t)s[j] * 64 + lane];
#pragma unroll
        for (int j = 0; j < 8; ++j)
            acc[j] += __builtin_amdgcn_cvt_pk_f32_fp8((int)u[j], false);
    }
    for (; i + 4 <= d; i += 4) {
        int s[4];
#pragma unroll
        for (int j = 0; j < 4; ++j) s[j] = csr_src[rs + i + j];
        unsigned short u[4];
#pragma unroll
        for (int j = 0; j < 4; ++j) u[j] = xf8[(size_t)s[j] * 64 + lane];
#pragma unroll
        for (int j = 0; j < 4; ++j)
            acc[j] += __builtin_amdgcn_cvt_pk_f32_fp8((int)u[j], false);
    }
    for (; i < d; ++i) {
        unsigned short u0 = xf8[(size_t)csr_src[rs + i] * 64 + lane];
        acc[0] += __builtin_amdgcn_cvt_pk_f32_fp8((int)u0, false);
    }
    f32x2 tot = ((acc[0] + acc[1]) + (acc[2] + acc[3]))
              + ((acc[4] + acc[5]) + (acc[6] + acc[7]));
    float inv = 1.0f / fmaxf((float)d, 1.0f);
    unsigned o = ((unsigned)f2bf(tot.y * inv) << 16) | (unsigned)f2bf(tot.x * inv);
    ((unsigned*)aggm)[(size_t)wid * 64 + lane] = o;
}

// ---- fused mgemm: stage [aggm bf16 | xf8->bf16] in LDS; h1 = relu(A@Bp1+b1)
//      kept in LDS; then zb8 = fp8(h1@W2l), rbufb = bf16(h1@W2r + b2) --------
__global__ void __launch_bounds__(256)
mgemm_fused_kernel(const unsigned short* __restrict__ aggm,
                   const unsigned char* __restrict__ xf8b,
                   const unsigned short* __restrict__ Bp1, const float* __restrict__ b1,
                   const unsigned short* __restrict__ Bp2, const float* __restrict__ b2,
                   unsigned char* __restrict__ zb8, unsigned short* __restrict__ rbufb,
                   int N) {
    __shared__ __align__(16) unsigned short alds[64 * LDA];
    int n0 = blockIdx.x * 64;
    int t = threadIdx.x;
#pragma unroll
    for (int i = 0; i < 4; ++i) {
        int cid = t + i * 256;
        int row = cid >> 4, ca = cid & 15;
        int gr = n0 + row;
        uint4 v = make_uint4(0, 0, 0, 0);
        if (gr < N) v = *(const uint4*)(aggm + (size_t)gr * 128 + ca * 8);
        *(uint4*)&alds[row * LDA + ca * 8] = v;
    }
#pragma unroll
    for (int i = 0; i < 4; ++i) {
        int cid = t + i * 256;
        int row = cid >> 4, cx = cid & 15;
        int gr = n0 + row;
        uint2 v8 = make_uint2(0u, 0u);
        if (gr < N) v8 = *(const uint2*)(xf8b + (size_t)gr * 128 + cx * 8);
        f32x2 f0 = __builtin_amdgcn_cvt_pk_f32_fp8((int)v8.x, false);
        f32x2 f1 = __builtin_amdgcn_cvt_pk_f32_fp8((int)v8.x, true);
        f32x2 f2 = __builtin_amdgcn_cvt_pk_f32_fp8((int)v8.y, false);
        f32x2 f3 = __builtin_amdgcn_cvt_pk_f32_fp8((int)v8.y, true);
        uint4 ov;
        ov.x = ((unsigned)f2bf(f0.y) << 16) | f2bf(f0.x);
        ov.y = ((unsigned)f2bf(f1.y) << 16) | f2bf(f1.x);
        ov.z = ((unsigned)f2bf(f2.y) << 16) | f2bf(f2.x);
        ov.w = ((unsigned)f2bf(f3.y) << 16) | f2bf(f3.x);
        *(uint4*)&alds[row * LDA + 128 + cx * 8] = ov;
    }
    __syncthreads();
    int wid = t >> 6, lane = t & 63;
    int l15 = lane & 15, g = lane >> 4;
    int col0 = wid * 64;
    f32x4 acc[4][4];
#pragma unroll
    for (int mf = 0; mf < 4; ++mf)
#pragma unroll
        for (int nf = 0; nf < 4; ++nf) acc[mf][nf] = (f32x4)(0.0f);
    for (int ks = 0; ks < 8; ++ks) {
        short8 af[4], bfr[4];
#pragma unroll
        for (int mf = 0; mf < 4; ++mf)
            af[mf] = *(const short8*)&alds[(mf * 16 + l15) * LDA + ks * 32 + g * 8];
#pragma unroll
        for (int nf = 0; nf < 4; ++nf)
            bfr[nf] = *(const short8*)&Bp1[((size_t)ks * 256 + col0 + nf * 16 + l15) * 32 + g * 8];
#pragma unroll
        for (int mf = 0; mf < 4; ++mf)
#pragma unroll
            for (int nf = 0; nf < 4; ++nf)
                acc[mf][nf] = __builtin_amdgcn_mfma_f32_16x16x32_bf16(
                    af[mf], bfr[nf], acc[mf][nf], 0, 0, 0);
    }
    float bc[4];
#pragma unroll
    for (int nf = 0; nf < 4; ++nf) bc[nf] = b1[col0 + nf * 16 + l15];
    __syncthreads();
#pragma unroll
    for (int mf = 0; mf < 4; ++mf) {
#pragma unroll
        for (int r = 0; r < 4; ++r) {
            int row = mf * 16 + g * 4 + r;
#pragma unroll
            for (int nf = 0; nf < 4; ++nf)
                alds[row * LDA + col0 + nf * 16 + l15] =
                    f2bf(fmaxf(acc[mf][nf][r] + bc[nf], 0.0f));
        }
    }
    __syncthreads();
    int wr = wid >> 1, wc = wid & 1;
    f32x4 acc2[2][3];
#pragma unroll
    for (int mf = 0; mf < 2; ++mf)
#pragma unroll
        for (int nf = 0; nf < 3; ++nf) acc2[mf][nf] = (f32x4)(0.0f);
    for (int ks = 0; ks < 8; ++ks) {
        short8 af[2], bfr[3];
#pragma unroll
        for (int mf = 0; mf < 2; ++mf)
            af[mf] = *(const short8*)&alds[(wr * 32 + mf * 16 + l15) * LDA + ks * 32 + g * 8];
#pragma unroll
        for (int nf = 0; nf < 3; ++nf)
            bfr[nf] = *(const short8*)&Bp2[((size_t)ks * 96 + wc * 48 + nf * 16 + l15) * 32 + g * 8];
#pragma unroll
        for (int mf = 0; mf < 2; ++mf)
#pragma unroll
            for (int nf = 0; nf < 3; ++nf)
                acc2[mf][nf] = __builtin_amdgcn_mfma_f32_16x16x32_bf16(
                    af[mf], bfr[nf], acc2[mf][nf], 0, 0, 0);
    }
#pragma unroll
    for (int nf = 0; nf < 3; ++nf) {
        int col = wc * 48 + nf * 16 + l15;
        float bb = (col >= 48 && col < 89) ? b2[col - 48] : 0.0f;
#pragma unroll
        for (int mf = 0; mf < 2; ++mf) {
            int rowb = n0 + wr * 32 + mf * 16 + g * 4;
#pragma unroll
            for (int r = 0; r < 4; ++r) {
                int row = rowb + r;
                if (row < N) {
                    float v = acc2[mf][nf][r];
                    if (col < 41) {
                        unsigned u = __builtin_amdgcn_cvt_pk_fp8_f32(v, 0.0f, 0, false);
                        zb8[(size_t)row * CPAD + col] = (unsigned char)(u & 0xff);
                    } else if (col >= 48 && col < 89) {
                        rbufb[(size_t)row * CPAD + (col - 48)] = f2bf(v + bb);
                    }
                }
            }
        }
    }
}

// -- gather2+final: 4 nodes/wave (16 lanes each, uint = 4 fp8), unroll-8/4 ---
__global__ void __launch_bounds__(256)
gather2_kernel(const unsigned* __restrict__ zp8, const unsigned short* __restrict__ rbufb,
               const int* __restrict__ row_start,
               const int* __restrict__ csr_src, float* __restrict__ out, int N) {
    int tid = blockIdx.x * 256 + threadIdx.x;
    int nid = tid >> 4;
    int l = tid & 15;
    if (nid >= N) return;
    int rs = row_start[nid];
    int d = row_start[nid + 1] - rs;
    f32x2 a2[4][2];
#pragma unroll
    for (int j = 0; j < 4; ++j) { a2[j][0] = (f32x2)(0.0f); a2[j][1] = (f32x2)(0.0f); }
    int i = 0;
    for (; i + 8 <= d; i += 8) {
        int s[8];
#pragma unroll
        for (int j = 0; j < 8; ++j) s[j] = csr_src[rs + i + j];
        unsigned u[8];
#pragma unroll
        for (int j = 0; j < 8; ++j) u[j] = zp8[(size_t)s[j] * 16 + l];
#pragma unroll
        for (int j = 0; j < 8; ++j) {
            a2[j & 3][0] += __builtin_amdgcn_cvt_pk_f32_fp8((int)u[j], false);
            a2[j & 3][1] += __builtin_amdgcn_cvt_pk_f32_fp8((int)u[j], true);
        }
    }
    for (; i + 4 <= d; i += 4) {
        int s[4];
#pragma unroll
        for (int j = 0; j < 4; ++j) s[j] = csr_src[rs + i + j];
        unsigned u[4];
#pragma unroll
        for (int j = 0; j < 4; ++j) u[j] = zp8[(size_t)s[j] * 16 + l];
#pragma unroll
        for (int j = 0; j < 4; ++j) {
            a2[j][0] += __builtin_amdgcn_cvt_pk_f32_fp8((int)u[j], false);
            a2[j][1] += __builtin_amdgcn_cvt_pk_f32_fp8((int)u[j], true);
        }
    }
    for (; i < d; ++i) {
        unsigned u0 = zp8[(size_t)csr_src[rs + i] * 16 + l];
        a2[0][0] += __builtin_amdgcn_cvt_pk_f32_fp8((int)u0, false);
        a2[0][1] += __builtin_amdgcn_cvt_pk_f32_fp8((int)u0, true);
    }
    f32x2 lo = (a2[0][0] + a2[1][0]) + (a2[2][0] + a2[3][0]);
    f32x2 hi = (a2[0][1] + a2[1][1]) + (a2[2][1] + a2[3][1]);
    float inv = 1.0f / fmaxf((float)d, 1.0f);
    ushort4 rb4 = *(const ushort4*)&rbufb[(size_t)nid * CPAD + 4 * l];
    float av[4] = {lo.x, lo.y, hi.x, hi.y};
    float rbv[4] = {bf2f(rb4.x), bf2f(rb4.y), bf2f(rb4.z), bf2f(rb4.w)};
    float v[4];
#pragma unroll
    for (int k = 0; k < 4; ++k) {
        int col = 4 * l + k;
        v[k] = (col < CLASSES) ? av[k] * inv + rbv[k] : -INFINITY;
    }
    float m = fmaxf(fmaxf(v[0], v[1]), fmaxf(v[2], v[3]));
#pragma unroll
    for (int off = 8; off; off >>= 1) m = fmaxf(m, __shfl_xor(m, off, 16));
    float s = 0.f;
#pragma unroll
    for (int k = 0; k < 4; ++k)
        s += (4 * l + k < CLASSES) ? expf(v[k] - m) : 0.0f;
#pragma unroll
    for (int off = 8; off; off >>= 1) s += __shfl_xor(s, off, 16);
    float lse = m + logf(s);
#pragma unroll
    for (int k = 0; k < 4; ++k) {
        int col = 4 * l + k;
        if (col < CLASSES) out[(size_t)nid * CLASSES + col] = v[k] - lse;
    }
}

extern "C" void kernel_launch(void* const* d_in, const int* in_sizes, int n_in,
                              void* d_out, int out_size, void* d_ws, size_t ws_size,
                              hipStream_t stream) {
    const float* x   = (const float*)d_in[0];
    const int*   ei  = (const int*)d_in[1];
    const float* W1l = (const float*)d_in[2];
    const float* W1r = (const float*)d_in[3];
    const float* b1  = (const float*)d_in[4];
    const float* W2l = (const float*)d_in[5];
    const float* W2r = (const float*)d_in[6];
    const float* b2  = (const float*)d_in[7];
    float* out = (float*)d_out;

    int N = in_sizes[0] / IN_FEATS;
    int E = in_sizes[1] / 2;
    const int* src = ei;
    const int* dst = ei + E;

    int NB   = (N + 127) >> BSH;
    int NBLK = (E + CHUNK - 1) / CHUNK;
    int L    = NB * NBLK;

    // ints: [mat L+1][blk_sums 512][row_start N+1][tmp E (u32)][csr_src E]
    int* ws_i      = (int*)d_ws;
    int* mat       = ws_i;
    int* blk_sums  = ws_i + (size_t)L + 1;
    int* row_start = blk_sums + 512;
    unsigned* tmp  = (unsigned*)(row_start + (size_t)N + 1);
    int* csr_src   = (int*)(tmp + (size_t)E);
    size_t int_bytes = ((size_t)L + 1 + 512 + (size_t)N + 1 + 2 * (size_t)E) * sizeof(int);
    char* p = (char*)d_ws + ((int_bytes + 15) & ~(size_t)15);
    unsigned*       xf8   = (unsigned*)p;                 p += (size_t)N * 128;
    unsigned short* aggm  = (unsigned short*)p;           p += (size_t)N * 128 * 2;
    unsigned short* Bp1   = (unsigned short*)p;           p += 65536 * 2;
    unsigned short* Bp2   = (unsigned short*)p;           p += 24576 * 2;
    unsigned char*  zb8   = (unsigned char*)p;            p += (size_t)N * CPAD;
    unsigned short* rbufb = (unsigned short*)p;

    long n4 = (long)N * 128 / 4;
    int XB = (int)((n4 + 255) / 256);
    int PB = (65536 + 24576) / 256;

    // ---- fused prepass: hist + x->fp8 + weight pack ----
    prepass_kernel<<<NBLK + XB + PB, 256, 0, stream>>>(
        dst, mat, E, NB, NBLK, x, xf8, n4, XB,
        W1l, W1r, W2l, W2r, Bp1, Bp2);

    int nscanM = (L + 1 + SCAN_BLK - 1) / SCAN_BLK;   // <= 512
    scanM1_kernel<<<nscanM, 256, 0, stream>>>(mat, blk_sums, L);
    scan2_kernel<<<1, 512, 0, stream>>>(blk_sums, nscanM);
    scanM3_kernel<<<(L + 1 + 255) / 256, 256, 0, stream>>>(mat, blk_sums, L);
    passB_kernel<<<NBLK, 256, 0, stream>>>(src, dst, mat, tmp, E, NB, NBLK);
    passC_kernel<<<NB, 256, 0, stream>>>(tmp, mat, row_start, csr_src, E, N, NB, NBLK);

    {
        long long threads = (long long)N * 64;
        gather1_kernel<<<(int)((threads + 255) / 256), 256, 0, stream>>>(
            (const unsigned short*)xf8, row_start, csr_src, aggm, N);
    }
    int gblocks = (N + 63) / 64;
    mgemm_fused_kernel<<<gblocks, 256, 0, stream>>>(aggm, (const unsigned char*)xf8,
                                                    Bp1, b1, Bp2, b2, zb8, rbufb, N);
    {
        long long threads = (long long)N * 16;
        gather2_kernel<<<(int)((threads + 255) / 256), 256, 0, stream>>>(
            (const unsigned*)zb8, rbufb, row_start, csr_src, out, N);
    }
}